// Round 1
// baseline (546.082 us; speedup 1.0000x reference)
//
#include <hip/hip_runtime.h>
#include <math.h>

#define NN 10000
#define NE 100000
#define NBATCH 64

__device__ __forceinline__ float lrelu(float v){ return v > 0.f ? v : 0.2f*v; }

// ---------------- utility: zero a region (re-poisoned ws each launch) ----------------
__global__ void zero_kernel(float* __restrict__ p, int nwords){
  int i = blockIdx.x*blockDim.x + threadIdx.x;
  if (i < nwords) p[i] = 0.f;
}

// ---------------- CSR build (by destination) + self-loop attr ----------------
__global__ void csr_count_kernel(const int* __restrict__ dst, const float* __restrict__ ea,
                                 int* __restrict__ deg, float* __restrict__ loop_sum){
  int e = blockIdx.x*blockDim.x + threadIdx.x;
  if (e < NE){
    int d = dst[e];
    atomicAdd(&deg[d], 1);
    atomicAdd(&loop_sum[d], ea[e]);
  }
}

__global__ __launch_bounds__(1024) void scan_kernel(const int* __restrict__ deg,
    const float* __restrict__ loop_sum, int* __restrict__ rowptr, float* __restrict__ loop_attr){
  __shared__ int s[1024];
  __shared__ int carry_s;
  int tid = threadIdx.x;
  if (tid == 0) carry_s = 0;
  __syncthreads();
  for (int base = 0; base < NN; base += 1024){
    int i = base + tid;
    int v = (i < NN) ? deg[i] : 0;
    s[tid] = v;
    __syncthreads();
    for (int off = 1; off < 1024; off <<= 1){
      int t = (tid >= off) ? s[tid - off] : 0;
      __syncthreads();
      s[tid] += t;
      __syncthreads();
    }
    int carry = carry_s;
    if (i < NN){
      rowptr[i] = carry + s[tid] - v;                       // exclusive scan
      loop_attr[i] = loop_sum[i] / fmaxf((float)v, 1.f);    // fill='mean'
    }
    __syncthreads();
    if (tid == 1023) carry_s = carry + s[1023];
    __syncthreads();
  }
  if (tid == 0) rowptr[NN] = carry_s;
}

__global__ void csr_fill_kernel(const int* __restrict__ src, const int* __restrict__ dst,
                                const float* __restrict__ ea, const int* __restrict__ rowptr,
                                int* __restrict__ rowctr, int* __restrict__ srcs,
                                float* __restrict__ eav){
  int e = blockIdx.x*blockDim.x + threadIdx.x;
  if (e < NE){
    int d = dst[e];
    int p = rowptr[d] + atomicAdd(&rowctr[d], 1);
    srcs[p] = src[e];
    eav[p] = ea[e];
  }
}

// ---------------- c1 low-rank precompute ----------------
// xl1[n,j] = x[n]*Ul[j] + CTl[type[n]][j];  xr1 likewise with Ur/CTr.
__global__ void precompute_c1_kernel(const float* __restrict__ vp_w, const float* __restrict__ vp_b,
                                     const float* __restrict__ type_emb,
                                     const float* __restrict__ wl, const float* __restrict__ bl,
                                     const float* __restrict__ wr, const float* __restrict__ br,
                                     float* __restrict__ Ul, float* __restrict__ CTl,
                                     float* __restrict__ Ur, float* __restrict__ CTr){
  int j = blockIdx.x*blockDim.x + threadIdx.x;
  if (j >= 1024) return;
  float ul=0.f, c0l=0.f, c1l=0.f, ur=0.f, c0r=0.f, c1r=0.f;
  for (int k=0; k<128; ++k){
    float a = wl[k*1024 + j], b = wr[k*1024 + j];
    float vw = vp_w[k], vb = vp_b[k], t0 = type_emb[k], t1 = type_emb[128+k];
    ul += vw*a; ur += vw*b;
    c0l += (vb+t0)*a; c1l += (vb+t1)*a;
    c0r += (vb+t0)*b; c1r += (vb+t1)*b;
  }
  Ul[j]=ul; Ur[j]=ur;
  CTl[j]      = c0l + bl[j];
  CTl[1024+j] = c1l + bl[j];
  CTr[j]      = c0r + br[j];
  CTr[1024+j] = c1r + br[j];
}

// ---------------- conv1: fused GATv2 with on-the-fly xl/xr (H=8, C=128) ----------------
__global__ __launch_bounds__(256) void conv1_kernel(
    const int* __restrict__ rowptr, const int* __restrict__ srcs, const float* __restrict__ eav,
    const float* __restrict__ loop_attr, const float* __restrict__ x, const int* __restrict__ ntype,
    const float* __restrict__ Ul, const float* __restrict__ CTl,
    const float* __restrict__ Ur, const float* __restrict__ CTr,
    const float* __restrict__ we, const float* __restrict__ att, const float* __restrict__ bias,
    float* __restrict__ out)
{
  const int TPH = 32;               // threads per head (8 heads x 32 = 256)
  int n = blockIdx.x;
  int tid = threadIdx.x;
  int ch0 = tid * 4;                // contiguous channels; head h = tid/32 aligned in-wave
  float wev[4], atv[4], biv[4], ulv[4], c0l[4], c1l[4], xrv[4];
  {
    float urv[4], c0r[4], c1r[4];
#pragma unroll
    for (int v=0; v<4; ++v){
      int ch = ch0 + v;
      wev[v] = we[ch]; atv[v] = att[ch]; biv[v] = bias[ch];
      ulv[v] = Ul[ch]; c0l[v] = CTl[ch]; c1l[v] = CTl[1024+ch];
      urv[v] = Ur[ch]; c0r[v] = CTr[ch]; c1r[v] = CTr[1024+ch];
    }
    float xn = x[n];
    int tn = ntype[n];
#pragma unroll
    for (int v=0; v<4; ++v) xrv[v] = xn*urv[v] + (tn ? c1r[v] : c0r[v]);
  }
  float acc[4] = {0.f,0.f,0.f,0.f};
  float m = -INFINITY, l = 0.f;
  int beg = rowptr[n], end = rowptr[n+1];
  for (int j = beg; j <= end; ++j){  // j==end is the self-loop
    int s; float ea;
    if (j < end){ s = srcs[j]; ea = eav[j]; }
    else        { s = n;       ea = loop_attr[n]; }
    float xs = x[s];
    int ts = ntype[s];
    float xlv[4];
#pragma unroll
    for (int v=0; v<4; ++v) xlv[v] = xs*ulv[v] + (ts ? c1l[v] : c0l[v]);
    float p = 0.f;
#pragma unroll
    for (int v=0; v<4; ++v){
      float z = xlv[v] + xrv[v] + ea*wev[v];
      p += atv[v]*lrelu(z);
    }
#pragma unroll
    for (int mm=1; mm<TPH; mm<<=1) p += __shfl_xor(p, mm, 64);
    float mn = fmaxf(m, p);
    float sc = __expf(m - mn);
    float pe = __expf(p - mn);
    l = l*sc + pe;
    m = mn;
#pragma unroll
    for (int v=0; v<4; ++v) acc[v] = acc[v]*sc + pe*xlv[v];
  }
  float inv = 1.f/l;
  size_t baseo = (size_t)n*1024 + ch0;
#pragma unroll
  for (int v=0; v<4; ++v) out[baseo+v] = lrelu(acc[v]*inv + biv[v]);
}

// ---------------- generic fused GATv2 conv reading materialized xl/xr ----------------
template<int H, int C, int THREADS, int VPT>
__global__ __launch_bounds__(THREADS) void conv_kernel(
    const int* __restrict__ rowptr, const int* __restrict__ srcs, const float* __restrict__ eav,
    const float* __restrict__ loop_attr,
    const float* __restrict__ xl, const float* __restrict__ xr,
    const float* __restrict__ we, const float* __restrict__ att, const float* __restrict__ bias,
    float* __restrict__ out)
{
  const int HC = H*C;
  const int TPH = THREADS/H;
  int n = blockIdx.x;
  int tid = threadIdx.x;
  int ch0 = tid * VPT;
  float wev[VPT], atv[VPT], biv[VPT], xrv[VPT], acc[VPT];
#pragma unroll
  for (int v=0; v<VPT; ++v){
    int ch = ch0+v;
    wev[v]=we[ch]; atv[v]=att[ch]; biv[v]=bias[ch];
    xrv[v]=xr[(size_t)n*HC+ch]; acc[v]=0.f;
  }
  float m=-INFINITY, l=0.f;
  int beg=rowptr[n], end=rowptr[n+1];
  for (int j=beg; j<=end; ++j){
    int s; float ea;
    if (j<end){ s=srcs[j]; ea=eav[j]; } else { s=n; ea=loop_attr[n]; }
    float xlv[VPT];
    const float* xp = xl + (size_t)s*HC + ch0;
    if constexpr (VPT == 4){
      float4 q = *(const float4*)xp;
      xlv[0]=q.x; xlv[1]=q.y; xlv[2]=q.z; xlv[3]=q.w;
    } else {
      float2 q = *(const float2*)xp;
      xlv[0]=q.x; xlv[1]=q.y;
    }
    float p=0.f;
#pragma unroll
    for (int v=0; v<VPT; ++v){
      float z = xlv[v]+xrv[v]+ea*wev[v];
      p += atv[v]*lrelu(z);
    }
#pragma unroll
    for (int mm=1; mm<TPH; mm<<=1) p += __shfl_xor(p, mm, 64);
    float mn=fmaxf(m,p), sc=__expf(m-mn), pe=__expf(p-mn);
    l=l*sc+pe; m=mn;
#pragma unroll
    for (int v=0; v<VPT; ++v) acc[v]=acc[v]*sc+pe*xlv[v];
  }
  float inv=1.f/l;
  size_t baseo=(size_t)n*HC+ch0;
#pragma unroll
  for (int v=0; v<VPT; ++v) out[baseo+v]=lrelu(acc[v]*inv+biv[v]);
}

// ---------------- fp32 tiled GEMM: Out[M,Nc] = A[M,K] @ W[K,Nc] + bias ----------------
__global__ __launch_bounds__(256) void gemm_bias_kernel(
    const float* __restrict__ A, const float* __restrict__ W, const float* __restrict__ bias,
    float* __restrict__ Out, int M, int Nc, int K)
{
  __shared__ float As[16][65];
  __shared__ float Bs[16][68];
  int tid = threadIdx.x;
  int row0 = blockIdx.y * 64;
  int col0 = blockIdx.x * 64;
  int tx = tid & 15, ty = tid >> 4;
  int am = tid >> 2, ak = (tid & 3) << 2;   // A tile 64x16, float4 along k
  int bk = tid >> 4, bn = (tid & 15) << 2;  // W tile 16x64, float4 along n
  float acc[4][4] = {};
  for (int k0 = 0; k0 < K; k0 += 16){
    float4 av;
    int ar = row0 + am;
    if (ar < M) av = *(const float4*)(A + (size_t)ar*K + k0 + ak);
    else        av = make_float4(0.f,0.f,0.f,0.f);
    As[ak+0][am] = av.x; As[ak+1][am] = av.y; As[ak+2][am] = av.z; As[ak+3][am] = av.w;
    float4 bv = *(const float4*)(W + (size_t)(k0+bk)*Nc + col0 + bn);
    *(float4*)&Bs[bk][bn] = bv;
    __syncthreads();
#pragma unroll
    for (int k=0; k<16; ++k){
      float a[4], bb[4];
#pragma unroll
      for (int i=0;i<4;++i)  a[i]  = As[k][ty*4+i];
#pragma unroll
      for (int jj=0;jj<4;++jj) bb[jj] = Bs[k][tx*4+jj];
#pragma unroll
      for (int i=0;i<4;++i)
#pragma unroll
        for (int jj=0;jj<4;++jj) acc[i][jj] += a[i]*bb[jj];
    }
    __syncthreads();
  }
#pragma unroll
  for (int i=0;i<4;++i){
    int r = row0 + ty*4 + i;
    if (r < M){
#pragma unroll
      for (int jj=0;jj<4;++jj){
        int c = col0 + tx*4 + jj;
        Out[(size_t)r*Nc + c] = acc[i][jj] + bias[c];
      }
    }
  }
}

// ---------------- masked mean-pool (accumulate) ----------------
__global__ __launch_bounds__(128) void pool_kernel(const float* __restrict__ h3,
    const int* __restrict__ ntype, const int* __restrict__ batch,
    float* __restrict__ sums, float* __restrict__ cnts)
{
  int n = blockIdx.x;
  if (ntype[n] != 0) return;
  int b = batch[n];
  int j = threadIdx.x;
  atomicAdd(&sums[b*128 + j], h3[(size_t)n*128 + j]);
  if (j == 0) atomicAdd(&cnts[b], 1.f);
}

// ---------------- MLP head: linear->LN->lrelu x2, final linear ----------------
__global__ __launch_bounds__(128) void head_kernel(
    const float* __restrict__ sums, const float* __restrict__ cnts,
    const float* __restrict__ m1w, const float* __restrict__ m1b,
    const float* __restrict__ g1, const float* __restrict__ b1,
    const float* __restrict__ m2w, const float* __restrict__ m2b,
    const float* __restrict__ g2, const float* __restrict__ b2,
    const float* __restrict__ m3w, const float* __restrict__ m3b,
    float* __restrict__ out)
{
  __shared__ float p[128];
  __shared__ float hb[128];
  __shared__ float red[128];
  int b = blockIdx.x, j = threadIdx.x;
  float cnt = fmaxf(cnts[b], 1.f);
  p[j] = sums[b*128 + j] / cnt;
  __syncthreads();
  float a = m1b[j];
  for (int k=0; k<128; ++k) a += p[k]*m1w[k*128 + j];
  red[j] = a; __syncthreads();
  for (int off=64; off>0; off>>=1){ if (j<off) red[j] += red[j+off]; __syncthreads(); }
  float mu = red[0] * (1.f/128.f);
  __syncthreads();
  float d = a - mu;
  red[j] = d*d; __syncthreads();
  for (int off=64; off>0; off>>=1){ if (j<off) red[j] += red[j+off]; __syncthreads(); }
  float var = red[0] * (1.f/128.f);
  __syncthreads();
  hb[j] = lrelu(d * rsqrtf(var + 1e-5f) * g1[j] + b1[j]);
  __syncthreads();
  float a2 = 0.f;
  if (j < 64){
    a2 = m2b[j];
    for (int k=0; k<128; ++k) a2 += hb[k]*m2w[k*64 + j];
  }
  red[j] = (j<64) ? a2 : 0.f; __syncthreads();
  for (int off=64; off>0; off>>=1){ if (j<off) red[j] += red[j+off]; __syncthreads(); }
  float mu2 = red[0] * (1.f/64.f);
  __syncthreads();
  float d2 = a2 - mu2;
  red[j] = (j<64) ? d2*d2 : 0.f; __syncthreads();
  for (int off=64; off>0; off>>=1){ if (j<off) red[j] += red[j+off]; __syncthreads(); }
  float var2 = red[0] * (1.f/64.f);
  __syncthreads();
  if (j < 64) hb[j] = lrelu(d2 * rsqrtf(var2 + 1e-5f) * g2[j] + b2[j]);
  __syncthreads();
  if (j == 0){
    float o = m3b[0];
    for (int k=0; k<64; ++k) o += hb[k]*m3w[k];
    out[b] = o;
  }
}

extern "C" void kernel_launch(void* const* d_in, const int* in_sizes, int n_in,
                              void* d_out, int out_size, void* d_ws, size_t ws_size,
                              hipStream_t stream)
{
  const float* x        = (const float*)d_in[0];
  const int*   ntype    = (const int*)d_in[1];
  const int*   ei       = (const int*)d_in[2];
  const float* eattr    = (const float*)d_in[3];
  const int*   batch    = (const int*)d_in[4];
  const float* vp_w     = (const float*)d_in[5];
  const float* vp_b     = (const float*)d_in[6];
  const float* type_emb = (const float*)d_in[7];
  const float* c1_wl = (const float*)d_in[8];  const float* c1_bl = (const float*)d_in[9];
  const float* c1_wr = (const float*)d_in[10]; const float* c1_br = (const float*)d_in[11];
  const float* c1_we = (const float*)d_in[12]; const float* c1_att= (const float*)d_in[13];
  const float* c1_bias=(const float*)d_in[14];
  const float* c2_wl = (const float*)d_in[15]; const float* c2_bl = (const float*)d_in[16];
  const float* c2_wr = (const float*)d_in[17]; const float* c2_br = (const float*)d_in[18];
  const float* c2_we = (const float*)d_in[19]; const float* c2_att= (const float*)d_in[20];
  const float* c2_bias=(const float*)d_in[21];
  const float* c3_wl = (const float*)d_in[22]; const float* c3_bl = (const float*)d_in[23];
  const float* c3_wr = (const float*)d_in[24]; const float* c3_br = (const float*)d_in[25];
  const float* c3_we = (const float*)d_in[26]; const float* c3_att= (const float*)d_in[27];
  const float* c3_bias=(const float*)d_in[28];
  const float* m1_w = (const float*)d_in[29]; const float* m1_b = (const float*)d_in[30];
  const float* ln1_g= (const float*)d_in[31]; const float* ln1_b= (const float*)d_in[32];
  const float* m2_w = (const float*)d_in[33]; const float* m2_b = (const float*)d_in[34];
  const float* ln2_g= (const float*)d_in[35]; const float* ln2_b= (const float*)d_in[36];
  const float* m3_w = (const float*)d_in[37]; const float* m3_b = (const float*)d_in[38];
  const int* esrc = ei;
  const int* edst = ei + NE;
  float* outp = (float*)d_out;
  (void)in_sizes; (void)n_in; (void)out_size; (void)ws_size;

  // ---- workspace arena (~89 MB) ----
  char* w = (char*)d_ws;
  auto alloc = [&](size_t bytes) -> void* {
    void* p = (void*)w;
    w += (bytes + 255) & ~(size_t)255;
    return p;
  };
  float* h1   = (float*)alloc((size_t)NN*1024*4);
  float* xl2  = (float*)alloc((size_t)NN*256*4);
  float* xr2  = (float*)alloc((size_t)NN*256*4);
  float* h2   = (float*)alloc((size_t)NN*256*4);
  float* xl3  = (float*)alloc((size_t)NN*128*4);
  float* xr3  = (float*)alloc((size_t)NN*128*4);
  float* h3   = (float*)alloc((size_t)NN*128*4);
  float* Ul   = (float*)alloc(1024*4);
  float* CTl  = (float*)alloc(2048*4);
  float* Ur   = (float*)alloc(1024*4);
  float* CTr  = (float*)alloc(2048*4);
  const int zero_words = NN + NN + NN + NBATCH*128 + NBATCH;
  float* zbase = (float*)alloc((size_t)zero_words*4);
  int*   deg      = (int*)zbase;
  int*   rowctr   = (int*)(zbase + NN);
  float* loop_sum = zbase + 2*NN;
  float* psums    = zbase + 3*NN;
  float* pcnts    = zbase + 3*NN + NBATCH*128;
  float* loop_attr= (float*)alloc((size_t)NN*4);
  int*   rowptr   = (int*)alloc((size_t)(NN+1)*4);
  int*   srcs     = (int*)alloc((size_t)NE*4);
  float* eav      = (float*)alloc((size_t)NE*4);

  // ---- pipeline ----
  zero_kernel<<<(zero_words+255)/256, 256, 0, stream>>>(zbase, zero_words);
  csr_count_kernel<<<(NE+255)/256, 256, 0, stream>>>(edst, eattr, deg, loop_sum);
  scan_kernel<<<1, 1024, 0, stream>>>(deg, loop_sum, rowptr, loop_attr);
  csr_fill_kernel<<<(NE+255)/256, 256, 0, stream>>>(esrc, edst, eattr, rowptr, rowctr, srcs, eav);
  precompute_c1_kernel<<<4, 256, 0, stream>>>(vp_w, vp_b, type_emb, c1_wl, c1_bl, c1_wr, c1_br,
                                              Ul, CTl, Ur, CTr);
  conv1_kernel<<<NN, 256, 0, stream>>>(rowptr, srcs, eav, loop_attr, x, ntype,
                                       Ul, CTl, Ur, CTr, c1_we, c1_att, c1_bias, h1);
  gemm_bias_kernel<<<dim3(4, (NN+63)/64), 256, 0, stream>>>(h1, c2_wl, c2_bl, xl2, NN, 256, 1024);
  gemm_bias_kernel<<<dim3(4, (NN+63)/64), 256, 0, stream>>>(h1, c2_wr, c2_br, xr2, NN, 256, 1024);
  conv_kernel<2,128,64,4><<<NN, 64, 0, stream>>>(rowptr, srcs, eav, loop_attr, xl2, xr2,
                                                 c2_we, c2_att, c2_bias, h2);
  gemm_bias_kernel<<<dim3(2, (NN+63)/64), 256, 0, stream>>>(h2, c3_wl, c3_bl, xl3, NN, 128, 256);
  gemm_bias_kernel<<<dim3(2, (NN+63)/64), 256, 0, stream>>>(h2, c3_wr, c3_br, xr3, NN, 128, 256);
  conv_kernel<1,128,64,2><<<NN, 64, 0, stream>>>(rowptr, srcs, eav, loop_attr, xl3, xr3,
                                                 c3_we, c3_att, c3_bias, h3);
  pool_kernel<<<NN, 128, 0, stream>>>(h3, ntype, batch, psums, pcnts);
  head_kernel<<<NBATCH, 128, 0, stream>>>(psums, pcnts, m1_w, m1_b, ln1_g, ln1_b,
                                          m2_w, m2_b, ln2_g, ln2_b, m3_w, m3_b, outp);
}

// Round 3
// 507.949 us; speedup vs baseline: 1.0751x; 1.0751x over previous
//
#include <hip/hip_runtime.h>
#include <math.h>

#define NN 10000
#define NE 100000
#define NBATCH 64

__device__ __forceinline__ float lrelu(float v){ return v > 0.f ? v : 0.2f*v; }

// ---------------- utility: zero a region (re-poisoned ws each launch) ----------------
__global__ void zero_kernel(float* __restrict__ p, int nwords){
  int i = blockIdx.x*blockDim.x + threadIdx.x;
  if (i < nwords) p[i] = 0.f;
}

// ---------------- CSR build (by destination) + self-loop attr ----------------
__global__ void csr_count_kernel(const int* __restrict__ dst, const float* __restrict__ ea,
                                 int* __restrict__ deg, float* __restrict__ loop_sum){
  int e = blockIdx.x*blockDim.x + threadIdx.x;
  if (e < NE){
    int d = dst[e];
    atomicAdd(&deg[d], 1);
    atomicAdd(&loop_sum[d], ea[e]);
  }
}

// shfl-based scan: 1 block, 1024 threads
__global__ __launch_bounds__(1024) void scan_kernel(const int* __restrict__ deg,
    const float* __restrict__ loop_sum, int* __restrict__ rowptr, float* __restrict__ loop_attr){
  __shared__ int wsum[16];
  __shared__ int carry_s;
  int tid = threadIdx.x;
  int lane = tid & 63, wid = tid >> 6;
  if (tid == 0) carry_s = 0;
  __syncthreads();
  for (int base = 0; base < NN; base += 1024){
    int i = base + tid;
    int v = (i < NN) ? deg[i] : 0;
    int incl = v;
#pragma unroll
    for (int off = 1; off < 64; off <<= 1){
      int t = __shfl_up(incl, off, 64);
      if (lane >= off) incl += t;
    }
    if (lane == 63) wsum[wid] = incl;
    __syncthreads();
    int pre = carry_s;
    for (int w = 0; w < wid; ++w) pre += wsum[w];
    if (i < NN){
      rowptr[i] = pre + incl - v;                           // exclusive scan
      loop_attr[i] = loop_sum[i] / fmaxf((float)v, 1.f);    // fill='mean'
    }
    __syncthreads();
    if (tid == 0){
      int t = 0;
      for (int w = 0; w < 16; ++w) t += wsum[w];
      carry_s += t;
    }
    __syncthreads();
  }
  if (tid == 0) rowptr[NN] = carry_s;
}

__global__ void csr_fill_kernel(const int* __restrict__ src, const int* __restrict__ dst,
                                const float* __restrict__ ea, const int* __restrict__ rowptr,
                                int* __restrict__ rowctr, int* __restrict__ srcs,
                                float* __restrict__ eav){
  int e = blockIdx.x*blockDim.x + threadIdx.x;
  if (e < NE){
    int d = dst[e];
    int p = rowptr[d] + atomicAdd(&rowctr[d], 1);
    srcs[p] = src[e];
    eav[p] = ea[e];
  }
}

// ---------------- c1 low-rank precompute ----------------
__global__ void precompute_c1_kernel(const float* __restrict__ vp_w, const float* __restrict__ vp_b,
                                     const float* __restrict__ type_emb,
                                     const float* __restrict__ wl, const float* __restrict__ bl,
                                     const float* __restrict__ wr, const float* __restrict__ br,
                                     float* __restrict__ Ul, float* __restrict__ CTl,
                                     float* __restrict__ Ur, float* __restrict__ CTr){
  int j = blockIdx.x*blockDim.x + threadIdx.x;
  if (j >= 1024) return;
  float ul=0.f, c0l=0.f, c1l=0.f, ur=0.f, c0r=0.f, c1r=0.f;
  for (int k=0; k<128; ++k){
    float a = wl[k*1024 + j], b = wr[k*1024 + j];
    float vw = vp_w[k], vb = vp_b[k], t0 = type_emb[k], t1 = type_emb[128+k];
    ul += vw*a; ur += vw*b;
    c0l += (vb+t0)*a; c1l += (vb+t1)*a;
    c0r += (vb+t0)*b; c1r += (vb+t1)*b;
  }
  Ul[j]=ul; Ur[j]=ur;
  CTl[j]      = c0l + bl[j];
  CTl[1024+j] = c1l + bl[j];
  CTr[j]      = c0r + br[j];
  CTr[1024+j] = c1r + br[j];
}

// ---------------- conv1: fused GATv2 with on-the-fly xl/xr (H=8, C=128) ----------------
__global__ __launch_bounds__(256) void conv1_kernel(
    const int* __restrict__ rowptr, const int* __restrict__ srcs, const float* __restrict__ eav,
    const float* __restrict__ loop_attr, const float* __restrict__ x, const int* __restrict__ ntype,
    const float* __restrict__ Ul, const float* __restrict__ CTl,
    const float* __restrict__ Ur, const float* __restrict__ CTr,
    const float* __restrict__ we, const float* __restrict__ att, const float* __restrict__ bias,
    float* __restrict__ out)
{
  const int TPH = 32;               // threads per head (8 heads x 32 = 256)
  int n = blockIdx.x;
  int tid = threadIdx.x;
  int ch0 = tid * 4;
  float wev[4], atv[4], biv[4], ulv[4], c0l[4], c1l[4], xrv[4];
  {
    float urv[4], c0r[4], c1r[4];
#pragma unroll
    for (int v=0; v<4; ++v){
      int ch = ch0 + v;
      wev[v] = we[ch]; atv[v] = att[ch]; biv[v] = bias[ch];
      ulv[v] = Ul[ch]; c0l[v] = CTl[ch]; c1l[v] = CTl[1024+ch];
      urv[v] = Ur[ch]; c0r[v] = CTr[ch]; c1r[v] = CTr[1024+ch];
    }
    float xn = x[n];
    int tn = ntype[n];
#pragma unroll
    for (int v=0; v<4; ++v) xrv[v] = xn*urv[v] + (tn ? c1r[v] : c0r[v]);
  }
  float acc[4] = {0.f,0.f,0.f,0.f};
  float m = -INFINITY, l = 0.f;
  int beg = rowptr[n], end = rowptr[n+1];
  for (int j = beg; j <= end; ++j){  // j==end is the self-loop
    int s; float ea;
    if (j < end){ s = srcs[j]; ea = eav[j]; }
    else        { s = n;       ea = loop_attr[n]; }
    float xs = x[s];
    int ts = ntype[s];
    float xlv[4];
#pragma unroll
    for (int v=0; v<4; ++v) xlv[v] = xs*ulv[v] + (ts ? c1l[v] : c0l[v]);
    float p = 0.f;
#pragma unroll
    for (int v=0; v<4; ++v){
      float z = xlv[v] + xrv[v] + ea*wev[v];
      p += atv[v]*lrelu(z);
    }
#pragma unroll
    for (int mm=1; mm<TPH; mm<<=1) p += __shfl_xor(p, mm, 64);
    float mn = fmaxf(m, p);
    float sc = __expf(m - mn);
    float pe = __expf(p - mn);
    l = l*sc + pe;
    m = mn;
#pragma unroll
    for (int v=0; v<4; ++v) acc[v] = acc[v]*sc + pe*xlv[v];
  }
  float inv = 1.f/l;
  size_t baseo = (size_t)n*1024 + ch0;
#pragma unroll
  for (int v=0; v<4; ++v) out[baseo+v] = lrelu(acc[v]*inv + biv[v]);
}

// ---------------- generic fused GATv2 conv (concat xl|xr input layout) ----------------
template<int H, int THREADS, int VPT, bool ONLY0>
__global__ __launch_bounds__(THREADS) void conv_kernel(
    const int* __restrict__ rowptr, const int* __restrict__ srcs, const float* __restrict__ eav,
    const float* __restrict__ loop_attr, const int* __restrict__ ntype,
    const float* __restrict__ X, int stride, int xr_off,
    const float* __restrict__ we, const float* __restrict__ att, const float* __restrict__ bias,
    float* __restrict__ out)
{
  const int HC = THREADS*VPT;
  const int TPH = THREADS/H;
  int n = blockIdx.x;
  if (ONLY0 && ntype[n] != 0) return;
  int tid = threadIdx.x;
  int ch0 = tid * VPT;
  float wev[VPT], atv[VPT], biv[VPT], xrv[VPT], acc[VPT];
#pragma unroll
  for (int v=0; v<VPT; ++v){
    int ch = ch0+v;
    wev[v]=we[ch]; atv[v]=att[ch]; biv[v]=bias[ch];
    xrv[v]=X[(size_t)n*stride + xr_off + ch]; acc[v]=0.f;
  }
  float m=-INFINITY, l=0.f;
  int beg=rowptr[n], end=rowptr[n+1];
  for (int j=beg; j<=end; ++j){
    int s; float ea;
    if (j<end){ s=srcs[j]; ea=eav[j]; } else { s=n; ea=loop_attr[n]; }
    float xlv[VPT];
    const float* xp = X + (size_t)s*stride + ch0;
    if constexpr (VPT == 4){
      float4 q = *(const float4*)xp;
      xlv[0]=q.x; xlv[1]=q.y; xlv[2]=q.z; xlv[3]=q.w;
    } else {
      float2 q = *(const float2*)xp;
      xlv[0]=q.x; xlv[1]=q.y;
    }
    float p=0.f;
#pragma unroll
    for (int v=0; v<VPT; ++v){
      float z = xlv[v]+xrv[v]+ea*wev[v];
      p += atv[v]*lrelu(z);
    }
#pragma unroll
    for (int mm=1; mm<TPH; mm<<=1) p += __shfl_xor(p, mm, 64);
    float mn=fmaxf(m,p), sc=__expf(m-mn), pe=__expf(p-mn);
    l=l*sc+pe; m=mn;
#pragma unroll
    for (int v=0; v<VPT; ++v) acc[v]=acc[v]*sc+pe*xlv[v];
  }
  float inv=1.f/l;
  size_t baseo=(size_t)n*HC+ch0;
#pragma unroll
  for (int v=0; v<VPT; ++v) out[baseo+v]=lrelu(acc[v]*inv+biv[v]);
}

// ---------------- fused dual-weight fp32 GEMM ----------------
// Out[M, 2*NcH] = [A@Wl + bl | A@Wr + br].  BM=64, BK=32, 256 threads,
// per-thread 4 x TN accs (TN = BN/16).  Grid: x = 2*NcH/BN, y = ceil(M/64).
template<int BN>
__global__ __launch_bounds__(256) void gemm_dual_kernel(
    const float* __restrict__ A,
    const float* __restrict__ Wl, const float* __restrict__ Wr,
    const float* __restrict__ bl, const float* __restrict__ br,
    float* __restrict__ Out, int M, int K, int NcH)
{
  const int TN = BN/16;
  __shared__ float As[32][68];   // stride 68: 16B-aligned rows (68*4 % 16 == 0)
  __shared__ float Bs[32][BN];
  int tid = threadIdx.x;
  int halfx = NcH/BN;
  int isR = blockIdx.x >= halfx;
  const float* W    = isR ? Wr : Wl;
  const float* bias = isR ? br : bl;
  int col0 = (blockIdx.x - (isR ? halfx : 0)) * BN;   // col within half
  int row0 = blockIdx.y * 64;
  int Nc2 = 2*NcH;
  int tx = tid & 15, ty = tid >> 4;

  float biasv[TN];
#pragma unroll
  for (int i=0;i<TN;++i) biasv[i] = bias[col0 + tx*TN + i];

  float acc[4][TN];
#pragma unroll
  for (int i=0;i<4;++i)
#pragma unroll
    for (int j=0;j<TN;++j) acc[i][j] = 0.f;

  for (int k0 = 0; k0 < K; k0 += 32){
    // stage A: 64x32, 2 float4/thread, store transposed As[k][m]
#pragma unroll
    for (int i=0;i<2;++i){
      int vecId = tid + 256*i;
      int r = vecId >> 3, kk = vecId & 7;
      int ar = row0 + r;
      float4 av = make_float4(0.f,0.f,0.f,0.f);
      if (ar < M) av = *(const float4*)(A + (size_t)ar*K + k0 + kk*4);
      As[kk*4+0][r] = av.x; As[kk*4+1][r] = av.y;
      As[kk*4+2][r] = av.z; As[kk*4+3][r] = av.w;
    }
    // stage B: 32xBN floats = 32*BN/4 float4s -> BN/32 iterations of 256 threads
#pragma unroll
    for (int i=0;i<BN/32;++i){
      int vecId = tid + 256*i;
      int kk = vecId / (BN/4), c4 = vecId % (BN/4);
      *(float4*)&Bs[kk][c4*4] = *(const float4*)(W + (size_t)(k0+kk)*NcH + col0 + c4*4);
    }
    __syncthreads();
#pragma unroll
    for (int k=0; k<32; ++k){
      float4 a = *(const float4*)&As[k][ty*4];
      float av[4] = {a.x, a.y, a.z, a.w};
      float bv[TN];
#pragma unroll
      for (int t4=0; t4<TN/4; ++t4){
        float4 b = *(const float4*)&Bs[k][tx*TN + t4*4];
        bv[t4*4+0]=b.x; bv[t4*4+1]=b.y; bv[t4*4+2]=b.z; bv[t4*4+3]=b.w;
      }
#pragma unroll
      for (int i=0;i<4;++i)
#pragma unroll
        for (int j=0;j<TN;++j) acc[i][j] += av[i]*bv[j];
    }
    __syncthreads();
  }
  // epilogue: concat layout, global col = blockIdx.x*BN + tx*TN
  int gcol = blockIdx.x*BN + tx*TN;
#pragma unroll
  for (int i=0;i<4;++i){
    int r = row0 + ty*4 + i;
    if (r < M){
#pragma unroll
      for (int t4=0; t4<TN/4; ++t4){
        float4 o;
        o.x = acc[i][t4*4+0] + biasv[t4*4+0];
        o.y = acc[i][t4*4+1] + biasv[t4*4+1];
        o.z = acc[i][t4*4+2] + biasv[t4*4+2];
        o.w = acc[i][t4*4+3] + biasv[t4*4+3];
        *(float4*)(Out + (size_t)r*Nc2 + gcol + t4*4) = o;
      }
    }
  }
}

// ---------------- fused pool (sorted batch, binary search) + MLP head ----------------
__device__ __forceinline__ int lbound(const int* __restrict__ a, int n, int key){
  int lo = 0, hi = n;
  while (lo < hi){ int mid = (lo+hi) >> 1; if (a[mid] < key) lo = mid+1; else hi = mid; }
  return lo;
}

__global__ __launch_bounds__(128) void head_kernel(
    const float* __restrict__ h3, const int* __restrict__ ntype, const int* __restrict__ batch,
    const float* __restrict__ m1w, const float* __restrict__ m1b,
    const float* __restrict__ g1, const float* __restrict__ b1,
    const float* __restrict__ m2w, const float* __restrict__ m2b,
    const float* __restrict__ g2, const float* __restrict__ b2,
    const float* __restrict__ m3w, const float* __restrict__ m3b,
    float* __restrict__ out)
{
  __shared__ float p[128];
  __shared__ float hb[128];
  __shared__ float red[128];
  int b = blockIdx.x, j = threadIdx.x;
  int lo = lbound(batch, NN, b);
  int hi = lbound(batch, NN, b+1);
  float s = 0.f; float cnt = 0.f;
  for (int n = lo; n < hi; ++n){
    if (ntype[n] == 0){
      s += h3[(size_t)n*128 + j];
      cnt += 1.f;
    }
  }
  p[j] = s / fmaxf(cnt, 1.f);
  __syncthreads();
  float a = m1b[j];
  for (int k=0; k<128; ++k) a += p[k]*m1w[k*128 + j];
  red[j] = a; __syncthreads();
  for (int off=64; off>0; off>>=1){ if (j<off) red[j] += red[j+off]; __syncthreads(); }
  float mu = red[0] * (1.f/128.f);
  __syncthreads();
  float d = a - mu;
  red[j] = d*d; __syncthreads();
  for (int off=64; off>0; off>>=1){ if (j<off) red[j] += red[j+off]; __syncthreads(); }
  float var = red[0] * (1.f/128.f);
  __syncthreads();
  hb[j] = lrelu(d * rsqrtf(var + 1e-5f) * g1[j] + b1[j]);
  __syncthreads();
  float a2 = 0.f;
  if (j < 64){
    a2 = m2b[j];
    for (int k=0; k<128; ++k) a2 += hb[k]*m2w[k*64 + j];
  }
  red[j] = (j<64) ? a2 : 0.f; __syncthreads();
  for (int off=64; off>0; off>>=1){ if (j<off) red[j] += red[j+off]; __syncthreads(); }
  float mu2 = red[0] * (1.f/64.f);
  __syncthreads();
  float d2 = a2 - mu2;
  red[j] = (j<64) ? d2*d2 : 0.f; __syncthreads();
  for (int off=64; off>0; off>>=1){ if (j<off) red[j] += red[j+off]; __syncthreads(); }
  float var2 = red[0] * (1.f/64.f);
  __syncthreads();
  if (j < 64) hb[j] = lrelu(d2 * rsqrtf(var2 + 1e-5f) * g2[j] + b2[j]);
  __syncthreads();
  if (j == 0){
    float o = m3b[0];
    for (int k=0; k<64; ++k) o += hb[k]*m3w[k];
    out[b] = o;
  }
}

extern "C" void kernel_launch(void* const* d_in, const int* in_sizes, int n_in,
                              void* d_out, int out_size, void* d_ws, size_t ws_size,
                              hipStream_t stream)
{
  const float* x        = (const float*)d_in[0];
  const int*   ntype    = (const int*)d_in[1];
  const int*   ei       = (const int*)d_in[2];
  const float* eattr    = (const float*)d_in[3];
  const int*   batch    = (const int*)d_in[4];
  const float* vp_w     = (const float*)d_in[5];
  const float* vp_b     = (const float*)d_in[6];
  const float* type_emb = (const float*)d_in[7];
  const float* c1_wl = (const float*)d_in[8];  const float* c1_bl = (const float*)d_in[9];
  const float* c1_wr = (const float*)d_in[10]; const float* c1_br = (const float*)d_in[11];
  const float* c1_we = (const float*)d_in[12]; const float* c1_att= (const float*)d_in[13];
  const float* c1_bias=(const float*)d_in[14];
  const float* c2_wl = (const float*)d_in[15]; const float* c2_bl = (const float*)d_in[16];
  const float* c2_wr = (const float*)d_in[17]; const float* c2_br = (const float*)d_in[18];
  const float* c2_we = (const float*)d_in[19]; const float* c2_att= (const float*)d_in[20];
  const float* c2_bias=(const float*)d_in[21];
  const float* c3_wl = (const float*)d_in[22]; const float* c3_bl = (const float*)d_in[23];
  const float* c3_wr = (const float*)d_in[24]; const float* c3_br = (const float*)d_in[25];
  const float* c3_we = (const float*)d_in[26]; const float* c3_att= (const float*)d_in[27];
  const float* c3_bias=(const float*)d_in[28];
  const float* m1_w = (const float*)d_in[29]; const float* m1_b = (const float*)d_in[30];
  const float* ln1_g= (const float*)d_in[31]; const float* ln1_b= (const float*)d_in[32];
  const float* m2_w = (const float*)d_in[33]; const float* m2_b = (const float*)d_in[34];
  const float* ln2_g= (const float*)d_in[35]; const float* ln2_b= (const float*)d_in[36];
  const float* m3_w = (const float*)d_in[37]; const float* m3_b = (const float*)d_in[38];
  const int* esrc = ei;
  const int* edst = ei + NE;
  float* outp = (float*)d_out;
  (void)in_sizes; (void)n_in; (void)out_size; (void)ws_size;

  // ---- workspace arena ----
  char* w = (char*)d_ws;
  auto alloc = [&](size_t bytes) -> void* {
    void* p = (void*)w;
    w += (bytes + 255) & ~(size_t)255;
    return p;
  };
  float* h1   = (float*)alloc((size_t)NN*1024*4);   // conv1 out
  float* X2   = (float*)alloc((size_t)NN*512*4);    // [xl2 | xr2]
  float* h2   = (float*)alloc((size_t)NN*256*4);    // conv2 out
  float* X3   = (float*)alloc((size_t)NN*256*4);    // [xl3 | xr3]
  float* h3   = (float*)alloc((size_t)NN*128*4);    // conv3 out (type0 rows only)
  float* Ul   = (float*)alloc(1024*4);
  float* CTl  = (float*)alloc(2048*4);
  float* Ur   = (float*)alloc(1024*4);
  float* CTr  = (float*)alloc(2048*4);
  const int zero_words = NN + NN + NN;               // deg, rowctr, loop_sum
  float* zbase = (float*)alloc((size_t)zero_words*4);
  int*   deg      = (int*)zbase;
  int*   rowctr   = (int*)(zbase + NN);
  float* loop_sum = zbase + 2*NN;
  float* loop_attr= (float*)alloc((size_t)NN*4);
  int*   rowptr   = (int*)alloc((size_t)(NN+1)*4);
  int*   srcs     = (int*)alloc((size_t)NE*4);
  float* eav      = (float*)alloc((size_t)NE*4);

  // ---- pipeline ----
  zero_kernel<<<(zero_words+255)/256, 256, 0, stream>>>(zbase, zero_words);
  csr_count_kernel<<<(NE+255)/256, 256, 0, stream>>>(edst, eattr, deg, loop_sum);
  scan_kernel<<<1, 1024, 0, stream>>>(deg, loop_sum, rowptr, loop_attr);
  csr_fill_kernel<<<(NE+255)/256, 256, 0, stream>>>(esrc, edst, eattr, rowptr, rowctr, srcs, eav);
  precompute_c1_kernel<<<4, 256, 0, stream>>>(vp_w, vp_b, type_emb, c1_wl, c1_bl, c1_wr, c1_br,
                                              Ul, CTl, Ur, CTr);
  conv1_kernel<<<NN, 256, 0, stream>>>(rowptr, srcs, eav, loop_attr, x, ntype,
                                       Ul, CTl, Ur, CTr, c1_we, c1_att, c1_bias, h1);
  // c2: X2[10000,512] = [h1@wl+bl | h1@wr+br], K=1024, NcH=256, BN=128 -> grid 4x157
  gemm_dual_kernel<128><<<dim3(4, (NN+63)/64), 256, 0, stream>>>(
      h1, c2_wl, c2_wr, c2_bl, c2_br, X2, NN, 1024, 256);
  conv_kernel<2,64,4,false><<<NN, 64, 0, stream>>>(rowptr, srcs, eav, loop_attr, ntype,
                                                   X2, 512, 256, c2_we, c2_att, c2_bias, h2);
  // c3: X3[10000,256] = [h2@wl+bl | h2@wr+br], K=256, NcH=128, BN=64 -> grid 4x157
  gemm_dual_kernel<64><<<dim3(4, (NN+63)/64), 256, 0, stream>>>(
      h2, c3_wl, c3_wr, c3_bl, c3_br, X3, NN, 256, 128);
  conv_kernel<1,64,2,true><<<NN, 64, 0, stream>>>(rowptr, srcs, eav, loop_attr, ntype,
                                                  X3, 256, 128, c3_we, c3_att, c3_bias, h3);
  head_kernel<<<NBATCH, 128, 0, stream>>>(h3, ntype, batch, m1_w, m1_b, ln1_g, ln1_b,
                                          m2_w, m2_b, ln2_g, ln2_b, m3_w, m3_b, outp);
}

// Round 4
// 414.825 us; speedup vs baseline: 1.3164x; 1.2245x over previous
//
#include <hip/hip_runtime.h>
#include <math.h>

#define NN 10000
#define NE 100000
#define NBATCH 64

typedef short bf16x8 __attribute__((ext_vector_type(8)));
typedef float f32x4 __attribute__((ext_vector_type(4)));

__device__ __forceinline__ float lrelu(float v){ return v > 0.f ? v : 0.2f*v; }

// fp32 -> bf16 round-to-nearest-even
__device__ __forceinline__ unsigned short f2bf(float x){
  unsigned int u = __float_as_uint(x);
  u += 0x7fffu + ((u >> 16) & 1u);
  return (unsigned short)(u >> 16);
}

// ---------------- utility: zero a region (re-poisoned ws each launch) ----------------
__global__ void zero_kernel(float* __restrict__ p, int nwords){
  int i = blockIdx.x*blockDim.x + threadIdx.x;
  if (i < nwords) p[i] = 0.f;
}

// ---------------- CSR build (by destination) + self-loop attr ----------------
__global__ void csr_count_kernel(const int* __restrict__ dst, const float* __restrict__ ea,
                                 int* __restrict__ deg, float* __restrict__ loop_sum){
  int e = blockIdx.x*blockDim.x + threadIdx.x;
  if (e < NE){
    int d = dst[e];
    atomicAdd(&deg[d], 1);
    atomicAdd(&loop_sum[d], ea[e]);
  }
}

// shfl-based scan: 1 block, 1024 threads
__global__ __launch_bounds__(1024) void scan_kernel(const int* __restrict__ deg,
    const float* __restrict__ loop_sum, int* __restrict__ rowptr, float* __restrict__ loop_attr){
  __shared__ int wsum[16];
  __shared__ int carry_s;
  int tid = threadIdx.x;
  int lane = tid & 63, wid = tid >> 6;
  if (tid == 0) carry_s = 0;
  __syncthreads();
  for (int base = 0; base < NN; base += 1024){
    int i = base + tid;
    int v = (i < NN) ? deg[i] : 0;
    int incl = v;
#pragma unroll
    for (int off = 1; off < 64; off <<= 1){
      int t = __shfl_up(incl, off, 64);
      if (lane >= off) incl += t;
    }
    if (lane == 63) wsum[wid] = incl;
    __syncthreads();
    int pre = carry_s;
    for (int w = 0; w < wid; ++w) pre += wsum[w];
    if (i < NN){
      rowptr[i] = pre + incl - v;                           // exclusive scan
      loop_attr[i] = loop_sum[i] / fmaxf((float)v, 1.f);    // fill='mean'
    }
    __syncthreads();
    if (tid == 0){
      int t = 0;
      for (int w = 0; w < 16; ++w) t += wsum[w];
      carry_s += t;
    }
    __syncthreads();
  }
  if (tid == 0) rowptr[NN] = carry_s;
}

__global__ void csr_fill_kernel(const int* __restrict__ src, const int* __restrict__ dst,
                                const float* __restrict__ ea, const int* __restrict__ rowptr,
                                int* __restrict__ rowctr, int* __restrict__ srcs,
                                float* __restrict__ eav){
  int e = blockIdx.x*blockDim.x + threadIdx.x;
  if (e < NE){
    int d = dst[e];
    int p = rowptr[d] + atomicAdd(&rowctr[d], 1);
    srcs[p] = src[e];
    eav[p] = ea[e];
  }
}

// ---------------- c1 low-rank precompute ----------------
__global__ void precompute_c1_kernel(const float* __restrict__ vp_w, const float* __restrict__ vp_b,
                                     const float* __restrict__ type_emb,
                                     const float* __restrict__ wl, const float* __restrict__ bl,
                                     const float* __restrict__ wr, const float* __restrict__ br,
                                     float* __restrict__ Ul, float* __restrict__ CTl,
                                     float* __restrict__ Ur, float* __restrict__ CTr){
  int j = blockIdx.x*blockDim.x + threadIdx.x;
  if (j >= 1024) return;
  float ul=0.f, c0l=0.f, c1l=0.f, ur=0.f, c0r=0.f, c1r=0.f;
  for (int k=0; k<128; ++k){
    float a = wl[k*1024 + j], b = wr[k*1024 + j];
    float vw = vp_w[k], vb = vp_b[k], t0 = type_emb[k], t1 = type_emb[128+k];
    ul += vw*a; ur += vw*b;
    c0l += (vb+t0)*a; c1l += (vb+t1)*a;
    c0r += (vb+t0)*b; c1r += (vb+t1)*b;
  }
  Ul[j]=ul; Ur[j]=ur;
  CTl[j]      = c0l + bl[j];
  CTl[1024+j] = c1l + bl[j];
  CTr[j]      = c0r + br[j];
  CTr[1024+j] = c1r + br[j];
}

// ---------------- weight transpose + cast: in[K][N] fp32 -> out[N][K] bf16 ----------------
__global__ __launch_bounds__(256) void transpose_cast_kernel(
    const float* __restrict__ in, unsigned short* __restrict__ out, int K, int N){
  __shared__ float t[64][65];
  int k0 = blockIdx.x*64, n0 = blockIdx.y*64;
  int tid = threadIdx.x;
  int lr = tid >> 4;              // 0..15
  int lc = (tid & 15) * 4;
#pragma unroll
  for (int i=0;i<4;++i){
    int r = lr + i*16;
    float4 v = *(const float4*)(in + (size_t)(k0+r)*N + n0 + lc);
    t[r][lc+0]=v.x; t[r][lc+1]=v.y; t[r][lc+2]=v.z; t[r][lc+3]=v.w;
  }
  __syncthreads();
  int sr = tid >> 3;              // 0..31
  int sc = (tid & 7) * 8;
#pragma unroll
  for (int i=0;i<2;++i){
    int n = sr + i*32;
    unsigned short tmp[8];
#pragma unroll
    for (int j=0;j<8;++j) tmp[j] = f2bf(t[sc+j][n]);
    unsigned short* op = out + (size_t)(n0+n)*K + k0 + sc;
    *(ushort4*)op       = make_ushort4(tmp[0],tmp[1],tmp[2],tmp[3]);
    *(ushort4*)(op + 4) = make_ushort4(tmp[4],tmp[5],tmp[6],tmp[7]);
  }
}

// ---------------- conv1: fused GATv2 with on-the-fly xl/xr (H=8, C=128), bf16 out --------
__global__ __launch_bounds__(256) void conv1_kernel(
    const int* __restrict__ rowptr, const int* __restrict__ srcs, const float* __restrict__ eav,
    const float* __restrict__ loop_attr, const float* __restrict__ x, const int* __restrict__ ntype,
    const float* __restrict__ Ul, const float* __restrict__ CTl,
    const float* __restrict__ Ur, const float* __restrict__ CTr,
    const float* __restrict__ we, const float* __restrict__ att, const float* __restrict__ bias,
    unsigned short* __restrict__ out)
{
  const int TPH = 32;               // threads per head (8 heads x 32 = 256)
  int n = blockIdx.x;
  int tid = threadIdx.x;
  int ch0 = tid * 4;
  float wev[4], atv[4], biv[4], ulv[4], c0l[4], c1l[4], xrv[4];
  {
    float urv[4], c0r[4], c1r[4];
#pragma unroll
    for (int v=0; v<4; ++v){
      int ch = ch0 + v;
      wev[v] = we[ch]; atv[v] = att[ch]; biv[v] = bias[ch];
      ulv[v] = Ul[ch]; c0l[v] = CTl[ch]; c1l[v] = CTl[1024+ch];
      urv[v] = Ur[ch]; c0r[v] = CTr[ch]; c1r[v] = CTr[1024+ch];
    }
    float xn = x[n];
    int tn = ntype[n];
#pragma unroll
    for (int v=0; v<4; ++v) xrv[v] = xn*urv[v] + (tn ? c1r[v] : c0r[v]);
  }
  float acc[4] = {0.f,0.f,0.f,0.f};
  float m = -INFINITY, l = 0.f;
  int beg = rowptr[n], end = rowptr[n+1];
  for (int j = beg; j <= end; ++j){  // j==end is the self-loop
    int s; float ea;
    if (j < end){ s = srcs[j]; ea = eav[j]; }
    else        { s = n;       ea = loop_attr[n]; }
    float xs = x[s];
    int ts = ntype[s];
    float xlv[4];
#pragma unroll
    for (int v=0; v<4; ++v) xlv[v] = xs*ulv[v] + (ts ? c1l[v] : c0l[v]);
    float p = 0.f;
#pragma unroll
    for (int v=0; v<4; ++v){
      float z = xlv[v] + xrv[v] + ea*wev[v];
      p += atv[v]*lrelu(z);
    }
#pragma unroll
    for (int mm=1; mm<TPH; mm<<=1) p += __shfl_xor(p, mm, 64);
    float mn = fmaxf(m, p);
    float sc = __expf(m - mn);
    float pe = __expf(p - mn);
    l = l*sc + pe;
    m = mn;
#pragma unroll
    for (int v=0; v<4; ++v) acc[v] = acc[v]*sc + pe*xlv[v];
  }
  float inv = 1.f/l;
  size_t baseo = (size_t)n*1024 + ch0;
  ushort4 o;
  o.x = f2bf(lrelu(acc[0]*inv + biv[0]));
  o.y = f2bf(lrelu(acc[1]*inv + biv[1]));
  o.z = f2bf(lrelu(acc[2]*inv + biv[2]));
  o.w = f2bf(lrelu(acc[3]*inv + biv[3]));
  *(ushort4*)(out + baseo) = o;
}

// ---------------- generic fused GATv2 conv (concat xl|xr input layout) ----------------
template<int H, int THREADS, int VPT, bool ONLY0, bool OUTBF>
__global__ __launch_bounds__(THREADS) void conv_kernel(
    const int* __restrict__ rowptr, const int* __restrict__ srcs, const float* __restrict__ eav,
    const float* __restrict__ loop_attr, const int* __restrict__ ntype,
    const float* __restrict__ X, int stride, int xr_off,
    const float* __restrict__ we, const float* __restrict__ att, const float* __restrict__ bias,
    void* __restrict__ out)
{
  const int HC = THREADS*VPT;
  const int TPH = THREADS/H;
  int n = blockIdx.x;
  if (ONLY0 && ntype[n] != 0) return;
  int tid = threadIdx.x;
  int ch0 = tid * VPT;
  float wev[VPT], atv[VPT], biv[VPT], xrv[VPT], acc[VPT];
#pragma unroll
  for (int v=0; v<VPT; ++v){
    int ch = ch0+v;
    wev[v]=we[ch]; atv[v]=att[ch]; biv[v]=bias[ch];
    xrv[v]=X[(size_t)n*stride + xr_off + ch]; acc[v]=0.f;
  }
  float m=-INFINITY, l=0.f;
  int beg=rowptr[n], end=rowptr[n+1];
  for (int j=beg; j<=end; ++j){
    int s; float ea;
    if (j<end){ s=srcs[j]; ea=eav[j]; } else { s=n; ea=loop_attr[n]; }
    float xlv[VPT];
    const float* xp = X + (size_t)s*stride + ch0;
    if constexpr (VPT == 4){
      float4 q = *(const float4*)xp;
      xlv[0]=q.x; xlv[1]=q.y; xlv[2]=q.z; xlv[3]=q.w;
    } else {
      float2 q = *(const float2*)xp;
      xlv[0]=q.x; xlv[1]=q.y;
    }
    float p=0.f;
#pragma unroll
    for (int v=0; v<VPT; ++v){
      float z = xlv[v]+xrv[v]+ea*wev[v];
      p += atv[v]*lrelu(z);
    }
#pragma unroll
    for (int mm=1; mm<TPH; mm<<=1) p += __shfl_xor(p, mm, 64);
    float mn=fmaxf(m,p), sc=__expf(m-mn), pe=__expf(p-mn);
    l=l*sc+pe; m=mn;
#pragma unroll
    for (int v=0; v<VPT; ++v) acc[v]=acc[v]*sc+pe*xlv[v];
  }
  float inv=1.f/l;
  size_t baseo=(size_t)n*HC+ch0;
  if constexpr (OUTBF){
    unsigned short* ob = (unsigned short*)out;
    static_assert(VPT == 4, "OUTBF path assumes VPT==4");
    ushort4 o;
    o.x = f2bf(lrelu(acc[0]*inv+biv[0]));
    o.y = f2bf(lrelu(acc[1]*inv+biv[1]));
    o.z = f2bf(lrelu(acc[2]*inv+biv[2]));
    o.w = f2bf(lrelu(acc[3]*inv+biv[3]));
    *(ushort4*)(ob + baseo) = o;
  } else {
    float* of = (float*)out;
#pragma unroll
    for (int v=0; v<VPT; ++v) of[baseo+v]=lrelu(acc[v]*inv+biv[v]);
  }
}

// ---------------- bf16 MFMA dual GEMM (LDS-free) ----------------
// Out[M, 2*NcH] fp32 = [A@Wl + bl | A@Wr + br]; A[M][K] bf16, WT[NcH][K] bf16.
// Block: 256 thr = 4 waves (2x2), tile 64x64; wave tile 32x32 = 2x2 mfma 16x16x32.
// Grid: x = 2*NcH/64 (first half L, second half R), y = ceil(M/64).
__global__ __launch_bounds__(256) void gemm_dual_mfma(
    const short* __restrict__ Abf,
    const short* __restrict__ WlT, const short* __restrict__ WrT,
    const float* __restrict__ bl, const float* __restrict__ br,
    float* __restrict__ Out, int M, int K, int NcH)
{
  int NC2 = 2*NcH;
  int halfx = NcH >> 6;
  int nb = blockIdx.x;
  int isR = nb >= halfx;
  const short* WT = isR ? WrT : WlT;
  const float* bias = isR ? br : bl;
  int col0 = (nb - (isR ? halfx : 0)) * 64;   // within half
  int gcol0 = nb * 64;                        // in concat output
  int row0 = blockIdx.y * 64;
  int tid = threadIdx.x;
  int lane = tid & 63, wave = tid >> 6;
  int wm = wave >> 1, wn = wave & 1;
  int quad = lane >> 4, l16 = lane & 15;

  int ar0 = row0 + wm*32 + l16;
  int ar1 = ar0 + 16;
  int car0 = ar0 < M ? ar0 : M-1;   // clamp: clamped rows never stored
  int car1 = ar1 < M ? ar1 : M-1;
  const short* ap0 = Abf + (size_t)car0*K + quad*8;
  const short* ap1 = Abf + (size_t)car1*K + quad*8;
  int brow = col0 + wn*32 + l16;
  const short* bp0 = WT + (size_t)brow*K + quad*8;
  const short* bp1 = bp0 + (size_t)16*K;
  float bias0 = bias[col0 + wn*32 + l16];
  float bias1 = bias[col0 + wn*32 + 16 + l16];

  f32x4 acc00 = {0.f,0.f,0.f,0.f}, acc01 = {0.f,0.f,0.f,0.f};
  f32x4 acc10 = {0.f,0.f,0.f,0.f}, acc11 = {0.f,0.f,0.f,0.f};
  for (int k0 = 0; k0 < K; k0 += 32){
    bf16x8 a0 = *(const bf16x8*)(ap0 + k0);
    bf16x8 a1 = *(const bf16x8*)(ap1 + k0);
    bf16x8 b0 = *(const bf16x8*)(bp0 + k0);
    bf16x8 b1 = *(const bf16x8*)(bp1 + k0);
    acc00 = __builtin_amdgcn_mfma_f32_16x16x32_bf16(a0, b0, acc00, 0, 0, 0);
    acc01 = __builtin_amdgcn_mfma_f32_16x16x32_bf16(a0, b1, acc01, 0, 0, 0);
    acc10 = __builtin_amdgcn_mfma_f32_16x16x32_bf16(a1, b0, acc10, 0, 0, 0);
    acc11 = __builtin_amdgcn_mfma_f32_16x16x32_bf16(a1, b1, acc11, 0, 0, 0);
  }
  int orow = row0 + wm*32 + quad*4;
  int oc0 = gcol0 + wn*32 + l16;
#pragma unroll
  for (int r = 0; r < 4; ++r){
    int rr = orow + r;
    if (rr < M){
      Out[(size_t)rr*NC2 + oc0]      = acc00[r] + bias0;
      Out[(size_t)rr*NC2 + oc0 + 16] = acc01[r] + bias1;
    }
    int rr2 = rr + 16;
    if (rr2 < M){
      Out[(size_t)rr2*NC2 + oc0]      = acc10[r] + bias0;
      Out[(size_t)rr2*NC2 + oc0 + 16] = acc11[r] + bias1;
    }
  }
}

// ---------------- fused pool (sorted batch, binary search) + MLP head ----------------
__device__ __forceinline__ int lbound(const int* __restrict__ a, int n, int key){
  int lo = 0, hi = n;
  while (lo < hi){ int mid = (lo+hi) >> 1; if (a[mid] < key) lo = mid+1; else hi = mid; }
  return lo;
}

__global__ __launch_bounds__(128) void head_kernel(
    const float* __restrict__ h3, const int* __restrict__ ntype, const int* __restrict__ batch,
    const float* __restrict__ m1w, const float* __restrict__ m1b,
    const float* __restrict__ g1, const float* __restrict__ b1,
    const float* __restrict__ m2w, const float* __restrict__ m2b,
    const float* __restrict__ g2, const float* __restrict__ b2,
    const float* __restrict__ m3w, const float* __restrict__ m3b,
    float* __restrict__ out)
{
  __shared__ float p[128];
  __shared__ float hb[128];
  __shared__ float red[128];
  int b = blockIdx.x, j = threadIdx.x;
  int lo = lbound(batch, NN, b);
  int hi = lbound(batch, NN, b+1);
  float s = 0.f; float cnt = 0.f;
  for (int n = lo; n < hi; ++n){
    if (ntype[n] == 0){
      s += h3[(size_t)n*128 + j];
      cnt += 1.f;
    }
  }
  p[j] = s / fmaxf(cnt, 1.f);
  __syncthreads();
  float a = m1b[j];
  for (int k=0; k<128; ++k) a += p[k]*m1w[k*128 + j];
  red[j] = a; __syncthreads();
  for (int off=64; off>0; off>>=1){ if (j<off) red[j] += red[j+off]; __syncthreads(); }
  float mu = red[0] * (1.f/128.f);
  __syncthreads();
  float d = a - mu;
  red[j] = d*d; __syncthreads();
  for (int off=64; off>0; off>>=1){ if (j<off) red[j] += red[j+off]; __syncthreads(); }
  float var = red[0] * (1.f/128.f);
  __syncthreads();
  hb[j] = lrelu(d * rsqrtf(var + 1e-5f) * g1[j] + b1[j]);
  __syncthreads();
  float a2 = 0.f;
  if (j < 64){
    a2 = m2b[j];
    for (int k=0; k<128; ++k) a2 += hb[k]*m2w[k*64 + j];
  }
  red[j] = (j<64) ? a2 : 0.f; __syncthreads();
  for (int off=64; off>0; off>>=1){ if (j<off) red[j] += red[j+off]; __syncthreads(); }
  float mu2 = red[0] * (1.f/64.f);
  __syncthreads();
  float d2 = a2 - mu2;
  red[j] = (j<64) ? d2*d2 : 0.f; __syncthreads();
  for (int off=64; off>0; off>>=1){ if (j<off) red[j] += red[j+off]; __syncthreads(); }
  float var2 = red[0] * (1.f/64.f);
  __syncthreads();
  if (j < 64) hb[j] = lrelu(d2 * rsqrtf(var2 + 1e-5f) * g2[j] + b2[j]);
  __syncthreads();
  if (j == 0){
    float o = m3b[0];
    for (int k=0; k<64; ++k) o += hb[k]*m3w[k];
    out[b] = o;
  }
}

extern "C" void kernel_launch(void* const* d_in, const int* in_sizes, int n_in,
                              void* d_out, int out_size, void* d_ws, size_t ws_size,
                              hipStream_t stream)
{
  const float* x        = (const float*)d_in[0];
  const int*   ntype    = (const int*)d_in[1];
  const int*   ei       = (const int*)d_in[2];
  const float* eattr    = (const float*)d_in[3];
  const int*   batch    = (const int*)d_in[4];
  const float* vp_w     = (const float*)d_in[5];
  const float* vp_b     = (const float*)d_in[6];
  const float* type_emb = (const float*)d_in[7];
  const float* c1_wl = (const float*)d_in[8];  const float* c1_bl = (const float*)d_in[9];
  const float* c1_wr = (const float*)d_in[10]; const float* c1_br = (const float*)d_in[11];
  const float* c1_we = (const float*)d_in[12]; const float* c1_att= (const float*)d_in[13];
  const float* c1_bias=(const float*)d_in[14];
  const float* c2_wl = (const float*)d_in[15]; const float* c2_bl = (const float*)d_in[16];
  const float* c2_wr = (const float*)d_in[17]; const float* c2_br = (const float*)d_in[18];
  const float* c2_we = (const float*)d_in[19]; const float* c2_att= (const float*)d_in[20];
  const float* c2_bias=(const float*)d_in[21];
  const float* c3_wl = (const float*)d_in[22]; const float* c3_bl = (const float*)d_in[23];
  const float* c3_wr = (const float*)d_in[24]; const float* c3_br = (const float*)d_in[25];
  const float* c3_we = (const float*)d_in[26]; const float* c3_att= (const float*)d_in[27];
  const float* c3_bias=(const float*)d_in[28];
  const float* m1_w = (const float*)d_in[29]; const float* m1_b = (const float*)d_in[30];
  const float* ln1_g= (const float*)d_in[31]; const float* ln1_b= (const float*)d_in[32];
  const float* m2_w = (const float*)d_in[33]; const float* m2_b = (const float*)d_in[34];
  const float* ln2_g= (const float*)d_in[35]; const float* ln2_b= (const float*)d_in[36];
  const float* m3_w = (const float*)d_in[37]; const float* m3_b = (const float*)d_in[38];
  const int* esrc = ei;
  const int* edst = ei + NE;
  float* outp = (float*)d_out;
  (void)in_sizes; (void)n_in; (void)out_size; (void)ws_size;

  // ---- workspace arena ----
  char* w = (char*)d_ws;
  auto alloc = [&](size_t bytes) -> void* {
    void* p = (void*)w;
    w += (bytes + 255) & ~(size_t)255;
    return p;
  };
  unsigned short* h1bf = (unsigned short*)alloc((size_t)NN*1024*2);  // conv1 out, bf16
  float* X2   = (float*)alloc((size_t)NN*512*4);    // [xl2 | xr2] fp32
  unsigned short* h2bf = (unsigned short*)alloc((size_t)NN*256*2);   // conv2 out, bf16
  float* X3   = (float*)alloc((size_t)NN*256*4);    // [xl3 | xr3] fp32
  float* h3   = (float*)alloc((size_t)NN*128*4);    // conv3 out (type0 rows only)
  unsigned short* W2lT = (unsigned short*)alloc((size_t)256*1024*2);
  unsigned short* W2rT = (unsigned short*)alloc((size_t)256*1024*2);
  unsigned short* W3lT = (unsigned short*)alloc((size_t)128*256*2);
  unsigned short* W3rT = (unsigned short*)alloc((size_t)128*256*2);
  float* Ul   = (float*)alloc(1024*4);
  float* CTl  = (float*)alloc(2048*4);
  float* Ur   = (float*)alloc(1024*4);
  float* CTr  = (float*)alloc(2048*4);
  const int zero_words = NN + NN + NN;               // deg, rowctr, loop_sum
  float* zbase = (float*)alloc((size_t)zero_words*4);
  int*   deg      = (int*)zbase;
  int*   rowctr   = (int*)(zbase + NN);
  float* loop_sum = zbase + 2*NN;
  float* loop_attr= (float*)alloc((size_t)NN*4);
  int*   rowptr   = (int*)alloc((size_t)(NN+1)*4);
  int*   srcs     = (int*)alloc((size_t)NE*4);
  float* eav      = (float*)alloc((size_t)NE*4);

  // ---- pipeline ----
  zero_kernel<<<(zero_words+255)/256, 256, 0, stream>>>(zbase, zero_words);
  csr_count_kernel<<<(NE+255)/256, 256, 0, stream>>>(edst, eattr, deg, loop_sum);
  scan_kernel<<<1, 1024, 0, stream>>>(deg, loop_sum, rowptr, loop_attr);
  csr_fill_kernel<<<(NE+255)/256, 256, 0, stream>>>(esrc, edst, eattr, rowptr, rowctr, srcs, eav);
  precompute_c1_kernel<<<4, 256, 0, stream>>>(vp_w, vp_b, type_emb, c1_wl, c1_bl, c1_wr, c1_br,
                                              Ul, CTl, Ur, CTr);
  transpose_cast_kernel<<<dim3(16,4), 256, 0, stream>>>(c2_wl, W2lT, 1024, 256);
  transpose_cast_kernel<<<dim3(16,4), 256, 0, stream>>>(c2_wr, W2rT, 1024, 256);
  transpose_cast_kernel<<<dim3(4,2),  256, 0, stream>>>(c3_wl, W3lT, 256, 128);
  transpose_cast_kernel<<<dim3(4,2),  256, 0, stream>>>(c3_wr, W3rT, 256, 128);
  conv1_kernel<<<NN, 256, 0, stream>>>(rowptr, srcs, eav, loop_attr, x, ntype,
                                       Ul, CTl, Ur, CTr, c1_we, c1_att, c1_bias, h1bf);
  // c2: X2[10000,512] = [h1@wl+bl | h1@wr+br], K=1024, NcH=256 -> grid 8x157
  gemm_dual_mfma<<<dim3(8, (NN+63)/64), 256, 0, stream>>>(
      (const short*)h1bf, (const short*)W2lT, (const short*)W2rT, c2_bl, c2_br, X2, NN, 1024, 256);
  conv_kernel<2,64,4,false,true><<<NN, 64, 0, stream>>>(rowptr, srcs, eav, loop_attr, ntype,
                                                   X2, 512, 256, c2_we, c2_att, c2_bias, h2bf);
  // c3: X3[10000,256] = [h2@wl+bl | h2@wr+br], K=256, NcH=128 -> grid 4x157
  gemm_dual_mfma<<<dim3(4, (NN+63)/64), 256, 0, stream>>>(
      (const short*)h2bf, (const short*)W3lT, (const short*)W3rT, c3_bl, c3_br, X3, NN, 256, 128);
  conv_kernel<1,64,2,true,false><<<NN, 64, 0, stream>>>(rowptr, srcs, eav, loop_attr, ntype,
                                                  X3, 256, 128, c3_we, c3_att, c3_bias, h3);
  head_kernel<<<NBATCH, 128, 0, stream>>>(h3, ntype, batch, m1_w, m1_b, ln1_g, ln1_b,
                                          m2_w, m2_b, ln2_g, ln2_b, m3_w, m3_b, outp);
}

// Round 5
// 411.965 us; speedup vs baseline: 1.3256x; 1.0069x over previous
//
#include <hip/hip_runtime.h>
#include <math.h>

#define NN 10000
#define NE 100000
#define NBATCH 64

typedef short bf16x8 __attribute__((ext_vector_type(8)));
typedef float f32x4 __attribute__((ext_vector_type(4)));

__device__ __forceinline__ float lrelu(float v){ return v > 0.f ? v : 0.2f*v; }

// fp32 -> bf16 round-to-nearest-even
__device__ __forceinline__ unsigned short f2bf(float x){
  unsigned int u = __float_as_uint(x);
  u += 0x7fffu + ((u >> 16) & 1u);
  return (unsigned short)(u >> 16);
}
__device__ __forceinline__ float bf2f(unsigned short u){
  return __uint_as_float(((unsigned int)u) << 16);
}

// ---------------- utility: zero a region (re-poisoned ws each launch) ----------------
__global__ void zero_kernel(float* __restrict__ p, int nwords){
  int i = blockIdx.x*blockDim.x + threadIdx.x;
  if (i < nwords) p[i] = 0.f;
}

// ---------------- CSR build (by destination) + self-loop attr ----------------
__global__ void csr_count_kernel(const int* __restrict__ dst, const float* __restrict__ ea,
                                 int* __restrict__ deg, float* __restrict__ loop_sum){
  int e = blockIdx.x*blockDim.x + threadIdx.x;
  if (e < NE){
    int d = dst[e];
    atomicAdd(&deg[d], 1);
    atomicAdd(&loop_sum[d], ea[e]);
  }
}

// shfl-based scan: 1 block, 1024 threads
__global__ __launch_bounds__(1024) void scan_kernel(const int* __restrict__ deg,
    const float* __restrict__ loop_sum, int* __restrict__ rowptr, float* __restrict__ loop_attr){
  __shared__ int wsum[16];
  __shared__ int carry_s;
  int tid = threadIdx.x;
  int lane = tid & 63, wid = tid >> 6;
  if (tid == 0) carry_s = 0;
  __syncthreads();
  for (int base = 0; base < NN; base += 1024){
    int i = base + tid;
    int v = (i < NN) ? deg[i] : 0;
    int incl = v;
#pragma unroll
    for (int off = 1; off < 64; off <<= 1){
      int t = __shfl_up(incl, off, 64);
      if (lane >= off) incl += t;
    }
    if (lane == 63) wsum[wid] = incl;
    __syncthreads();
    int pre = carry_s;
    for (int w = 0; w < wid; ++w) pre += wsum[w];
    if (i < NN){
      rowptr[i] = pre + incl - v;                           // exclusive scan
      loop_attr[i] = loop_sum[i] / fmaxf((float)v, 1.f);    // fill='mean'
    }
    __syncthreads();
    if (tid == 0){
      int t = 0;
      for (int w = 0; w < 16; ++w) t += wsum[w];
      carry_s += t;
    }
    __syncthreads();
  }
  if (tid == 0) rowptr[NN] = carry_s;
}

__global__ void csr_fill_kernel(const int* __restrict__ src, const int* __restrict__ dst,
                                const float* __restrict__ ea, const int* __restrict__ rowptr,
                                int* __restrict__ rowctr, int* __restrict__ srcs,
                                float* __restrict__ eav){
  int e = blockIdx.x*blockDim.x + threadIdx.x;
  if (e < NE){
    int d = dst[e];
    int p = rowptr[d] + atomicAdd(&rowctr[d], 1);
    srcs[p] = src[e];
    eav[p] = ea[e];
  }
}

// ---------------- c1 low-rank precompute ----------------
__global__ void precompute_c1_kernel(const float* __restrict__ vp_w, const float* __restrict__ vp_b,
                                     const float* __restrict__ type_emb,
                                     const float* __restrict__ wl, const float* __restrict__ bl,
                                     const float* __restrict__ wr, const float* __restrict__ br,
                                     float* __restrict__ Ul, float* __restrict__ CTl,
                                     float* __restrict__ Ur, float* __restrict__ CTr){
  int j = blockIdx.x*blockDim.x + threadIdx.x;
  if (j >= 1024) return;
  float ul=0.f, c0l=0.f, c1l=0.f, ur=0.f, c0r=0.f, c1r=0.f;
  for (int k=0; k<128; ++k){
    float a = wl[k*1024 + j], b = wr[k*1024 + j];
    float vw = vp_w[k], vb = vp_b[k], t0 = type_emb[k], t1 = type_emb[128+k];
    ul += vw*a; ur += vw*b;
    c0l += (vb+t0)*a; c1l += (vb+t1)*a;
    c0r += (vb+t0)*b; c1r += (vb+t1)*b;
  }
  Ul[j]=ul; Ur[j]=ur;
  CTl[j]      = c0l + bl[j];
  CTl[1024+j] = c1l + bl[j];
  CTr[j]      = c0r + br[j];
  CTr[1024+j] = c1r + br[j];
}

// ---------------- weight transpose + cast: in[K][N] fp32 -> out[N][K] bf16 ----------------
__global__ __launch_bounds__(256) void transpose_cast_kernel(
    const float* __restrict__ in, unsigned short* __restrict__ out, int K, int N){
  __shared__ float t[64][65];
  int k0 = blockIdx.x*64, n0 = blockIdx.y*64;
  int tid = threadIdx.x;
  int lr = tid >> 4;              // 0..15
  int lc = (tid & 15) * 4;
#pragma unroll
  for (int i=0;i<4;++i){
    int r = lr + i*16;
    float4 v = *(const float4*)(in + (size_t)(k0+r)*N + n0 + lc);
    t[r][lc+0]=v.x; t[r][lc+1]=v.y; t[r][lc+2]=v.z; t[r][lc+3]=v.w;
  }
  __syncthreads();
  int sr = tid >> 3;              // 0..31
  int sc = (tid & 7) * 8;
#pragma unroll
  for (int i=0;i<2;++i){
    int n = sr + i*32;
    unsigned short tmp[8];
#pragma unroll
    for (int j=0;j<8;++j) tmp[j] = f2bf(t[sc+j][n]);
    unsigned short* op = out + (size_t)(n0+n)*K + k0 + sc;
    *(ushort4*)op       = make_ushort4(tmp[0],tmp[1],tmp[2],tmp[3]);
    *(ushort4*)(op + 4) = make_ushort4(tmp[4],tmp[5],tmp[6],tmp[7]);
  }
}

// ---------------- conv1: fused GATv2 with on-the-fly xl/xr (H=8, C=128), bf16 out --------
__global__ __launch_bounds__(256) void conv1_kernel(
    const int* __restrict__ rowptr, const int* __restrict__ srcs, const float* __restrict__ eav,
    const float* __restrict__ loop_attr, const float* __restrict__ x, const int* __restrict__ ntype,
    const float* __restrict__ Ul, const float* __restrict__ CTl,
    const float* __restrict__ Ur, const float* __restrict__ CTr,
    const float* __restrict__ we, const float* __restrict__ att, const float* __restrict__ bias,
    unsigned short* __restrict__ out)
{
  const int TPH = 32;               // threads per head (8 heads x 32 = 256)
  int n = blockIdx.x;
  int tid = threadIdx.x;
  int ch0 = tid * 4;
  float wev[4], atv[4], biv[4], ulv[4], c0l[4], c1l[4], xrv[4];
  {
    float urv[4], c0r[4], c1r[4];
#pragma unroll
    for (int v=0; v<4; ++v){
      int ch = ch0 + v;
      wev[v] = we[ch]; atv[v] = att[ch]; biv[v] = bias[ch];
      ulv[v] = Ul[ch]; c0l[v] = CTl[ch]; c1l[v] = CTl[1024+ch];
      urv[v] = Ur[ch]; c0r[v] = CTr[ch]; c1r[v] = CTr[1024+ch];
    }
    float xn = x[n];
    int tn = ntype[n];
#pragma unroll
    for (int v=0; v<4; ++v) xrv[v] = xn*urv[v] + (tn ? c1r[v] : c0r[v]);
  }
  float acc[4] = {0.f,0.f,0.f,0.f};
  float m = -INFINITY, l = 0.f;
  int beg = rowptr[n], end = rowptr[n+1];
  for (int j = beg; j <= end; ++j){  // j==end is the self-loop
    int s; float ea;
    if (j < end){ s = srcs[j]; ea = eav[j]; }
    else        { s = n;       ea = loop_attr[n]; }
    float xs = x[s];
    int ts = ntype[s];
    float xlv[4];
#pragma unroll
    for (int v=0; v<4; ++v) xlv[v] = xs*ulv[v] + (ts ? c1l[v] : c0l[v]);
    float p = 0.f;
#pragma unroll
    for (int v=0; v<4; ++v){
      float z = xlv[v] + xrv[v] + ea*wev[v];
      p += atv[v]*lrelu(z);
    }
#pragma unroll
    for (int mm=1; mm<TPH; mm<<=1) p += __shfl_xor(p, mm, 64);
    float mn = fmaxf(m, p);
    float sc = __expf(m - mn);
    float pe = __expf(p - mn);
    l = l*sc + pe;
    m = mn;
#pragma unroll
    for (int v=0; v<4; ++v) acc[v] = acc[v]*sc + pe*xlv[v];
  }
  float inv = 1.f/l;
  size_t baseo = (size_t)n*1024 + ch0;
  ushort4 o;
  o.x = f2bf(lrelu(acc[0]*inv + biv[0]));
  o.y = f2bf(lrelu(acc[1]*inv + biv[1]));
  o.z = f2bf(lrelu(acc[2]*inv + biv[2]));
  o.w = f2bf(lrelu(acc[3]*inv + biv[3]));
  *(ushort4*)(out + baseo) = o;
}

// ---------------- generic fused GATv2 conv (concat xl|xr input layout) ----------------
template<int H, int THREADS, int VPT, bool ONLY0, bool OUTBF, bool INBF>
__global__ __launch_bounds__(THREADS) void conv_kernel(
    const int* __restrict__ rowptr, const int* __restrict__ srcs, const float* __restrict__ eav,
    const float* __restrict__ loop_attr, const int* __restrict__ ntype,
    const void* __restrict__ Xv, int stride, int xr_off,
    const float* __restrict__ we, const float* __restrict__ att, const float* __restrict__ bias,
    void* __restrict__ out)
{
  const int HC = THREADS*VPT;
  const int TPH = THREADS/H;
  int n = blockIdx.x;
  if (ONLY0 && ntype[n] != 0) return;
  int tid = threadIdx.x;
  int ch0 = tid * VPT;
  const float* Xf = (const float*)Xv;
  const unsigned short* Xb = (const unsigned short*)Xv;
  float wev[VPT], atv[VPT], biv[VPT], xrv[VPT], acc[VPT];
#pragma unroll
  for (int v=0; v<VPT; ++v){
    int ch = ch0+v;
    wev[v]=we[ch]; atv[v]=att[ch]; biv[v]=bias[ch];
    acc[v]=0.f;
  }
  if constexpr (INBF){
    static_assert(!INBF || VPT == 4, "INBF path assumes VPT==4");
    ushort4 q = *(const ushort4*)(Xb + (size_t)n*stride + xr_off + ch0);
    xrv[0]=bf2f(q.x); xrv[1]=bf2f(q.y); xrv[2]=bf2f(q.z); xrv[3]=bf2f(q.w);
  } else {
#pragma unroll
    for (int v=0; v<VPT; ++v) xrv[v]=Xf[(size_t)n*stride + xr_off + ch0+v];
  }
  float m=-INFINITY, l=0.f;
  int beg=rowptr[n], end=rowptr[n+1];
  for (int j=beg; j<=end; ++j){
    int s; float ea;
    if (j<end){ s=srcs[j]; ea=eav[j]; } else { s=n; ea=loop_attr[n]; }
    float xlv[VPT];
    if constexpr (INBF){
      ushort4 q = *(const ushort4*)(Xb + (size_t)s*stride + ch0);
      xlv[0]=bf2f(q.x); xlv[1]=bf2f(q.y); xlv[2]=bf2f(q.z); xlv[3]=bf2f(q.w);
    } else if constexpr (VPT == 4){
      float4 q = *(const float4*)(Xf + (size_t)s*stride + ch0);
      xlv[0]=q.x; xlv[1]=q.y; xlv[2]=q.z; xlv[3]=q.w;
    } else {
      float2 q = *(const float2*)(Xf + (size_t)s*stride + ch0);
      xlv[0]=q.x; xlv[1]=q.y;
    }
    float p=0.f;
#pragma unroll
    for (int v=0; v<VPT; ++v){
      float z = xlv[v]+xrv[v]+ea*wev[v];
      p += atv[v]*lrelu(z);
    }
#pragma unroll
    for (int mm=1; mm<TPH; mm<<=1) p += __shfl_xor(p, mm, 64);
    float mn=fmaxf(m,p), sc=__expf(m-mn), pe=__expf(p-mn);
    l=l*sc+pe; m=mn;
#pragma unroll
    for (int v=0; v<VPT; ++v) acc[v]=acc[v]*sc+pe*xlv[v];
  }
  float inv=1.f/l;
  size_t baseo=(size_t)n*HC+ch0;
  if constexpr (OUTBF){
    unsigned short* ob = (unsigned short*)out;
    static_assert(!OUTBF || VPT == 4, "OUTBF path assumes VPT==4");
    ushort4 o;
    o.x = f2bf(lrelu(acc[0]*inv+biv[0]));
    o.y = f2bf(lrelu(acc[1]*inv+biv[1]));
    o.z = f2bf(lrelu(acc[2]*inv+biv[2]));
    o.w = f2bf(lrelu(acc[3]*inv+biv[3]));
    *(ushort4*)(ob + baseo) = o;
  } else {
    float* of = (float*)out;
#pragma unroll
    for (int v=0; v<VPT; ++v) of[baseo+v]=lrelu(acc[v]*inv+biv[v]);
  }
}

// ---------------- bf16 MFMA dual GEMM (LDS-free, XCD-swizzled) ----------------
// Out[M, 2*NcH] = [A@Wl + bl | A@Wr + br]; A[M][K] bf16, WT[NcH][K] bf16.
// Block: 256 thr = 4 waves (2x2), tile 64x64; wave tile 32x32 = 2x2 mfma 16x16x32.
// 1D grid, swizzled so all column-groups of one row-group run on ONE XCD
// (A strip fetched once into that XCD's L2). cgrid = NC2/64, rgrid = ceil(M/64);
// launch 8*cgrid*ceil(rgrid/8) blocks.
template<bool OUTBF>
__global__ __launch_bounds__(256) void gemm_dual_mfma(
    const short* __restrict__ Abf,
    const short* __restrict__ WlT, const short* __restrict__ WrT,
    const float* __restrict__ bl, const float* __restrict__ br,
    void* __restrict__ Out, int M, int K, int NcH, int cgrid, int rgrid)
{
  int id = blockIdx.x;
  int xcd = id & 7;            // HW round-robin workgroup->XCD heuristic
  int slot = id >> 3;
  int nb = slot % cgrid;       // column group: consecutive slots on one XCD
  int rowgroup = (slot / cgrid) * 8 + xcd;
  if (rowgroup >= rgrid) return;
  int row0 = rowgroup * 64;

  int NC2 = 2*NcH;
  int halfx = NcH >> 6;
  int isR = nb >= halfx;
  const short* WT = isR ? WrT : WlT;
  const float* bias = isR ? br : bl;
  int col0 = (nb - (isR ? halfx : 0)) * 64;   // within half
  int gcol0 = nb * 64;                        // in concat output
  int tid = threadIdx.x;
  int lane = tid & 63, wave = tid >> 6;
  int wm = wave >> 1, wn = wave & 1;
  int quad = lane >> 4, l16 = lane & 15;

  int ar0 = row0 + wm*32 + l16;
  int ar1 = ar0 + 16;
  int car0 = ar0 < M ? ar0 : M-1;   // clamp: clamped rows never stored
  int car1 = ar1 < M ? ar1 : M-1;
  const short* ap0 = Abf + (size_t)car0*K + quad*8;
  const short* ap1 = Abf + (size_t)car1*K + quad*8;
  int brow = col0 + wn*32 + l16;
  const short* bp0 = WT + (size_t)brow*K + quad*8;
  const short* bp1 = bp0 + (size_t)16*K;
  float bias0 = bias[col0 + wn*32 + l16];
  float bias1 = bias[col0 + wn*32 + 16 + l16];

  f32x4 acc00 = {0.f,0.f,0.f,0.f}, acc01 = {0.f,0.f,0.f,0.f};
  f32x4 acc10 = {0.f,0.f,0.f,0.f}, acc11 = {0.f,0.f,0.f,0.f};
  for (int k0 = 0; k0 < K; k0 += 32){
    bf16x8 a0 = *(const bf16x8*)(ap0 + k0);
    bf16x8 a1 = *(const bf16x8*)(ap1 + k0);
    bf16x8 b0 = *(const bf16x8*)(bp0 + k0);
    bf16x8 b1 = *(const bf16x8*)(bp1 + k0);
    acc00 = __builtin_amdgcn_mfma_f32_16x16x32_bf16(a0, b0, acc00, 0, 0, 0);
    acc01 = __builtin_amdgcn_mfma_f32_16x16x32_bf16(a0, b1, acc01, 0, 0, 0);
    acc10 = __builtin_amdgcn_mfma_f32_16x16x32_bf16(a1, b0, acc10, 0, 0, 0);
    acc11 = __builtin_amdgcn_mfma_f32_16x16x32_bf16(a1, b1, acc11, 0, 0, 0);
  }
  int orow = row0 + wm*32 + quad*4;
  int oc0 = gcol0 + wn*32 + l16;
#pragma unroll
  for (int r = 0; r < 4; ++r){
    int rr = orow + r;
    int rr2 = rr + 16;
    if constexpr (OUTBF){
      unsigned short* ob = (unsigned short*)Out;
      if (rr < M){
        ob[(size_t)rr*NC2 + oc0]      = f2bf(acc00[r] + bias0);
        ob[(size_t)rr*NC2 + oc0 + 16] = f2bf(acc01[r] + bias1);
      }
      if (rr2 < M){
        ob[(size_t)rr2*NC2 + oc0]      = f2bf(acc10[r] + bias0);
        ob[(size_t)rr2*NC2 + oc0 + 16] = f2bf(acc11[r] + bias1);
      }
    } else {
      float* of = (float*)Out;
      if (rr < M){
        of[(size_t)rr*NC2 + oc0]      = acc00[r] + bias0;
        of[(size_t)rr*NC2 + oc0 + 16] = acc01[r] + bias1;
      }
      if (rr2 < M){
        of[(size_t)rr2*NC2 + oc0]      = acc10[r] + bias0;
        of[(size_t)rr2*NC2 + oc0 + 16] = acc11[r] + bias1;
      }
    }
  }
}

// ---------------- fused pool (sorted batch, binary search) + MLP head ----------------
__device__ __forceinline__ int lbound(const int* __restrict__ a, int n, int key){
  int lo = 0, hi = n;
  while (lo < hi){ int mid = (lo+hi) >> 1; if (a[mid] < key) lo = mid+1; else hi = mid; }
  return lo;
}

__global__ __launch_bounds__(128) void head_kernel(
    const float* __restrict__ h3, const int* __restrict__ ntype, const int* __restrict__ batch,
    const float* __restrict__ m1w, const float* __restrict__ m1b,
    const float* __restrict__ g1, const float* __restrict__ b1,
    const float* __restrict__ m2w, const float* __restrict__ m2b,
    const float* __restrict__ g2, const float* __restrict__ b2,
    const float* __restrict__ m3w, const float* __restrict__ m3b,
    float* __restrict__ out)
{
  __shared__ float p[128];
  __shared__ float hb[128];
  __shared__ float red[128];
  int b = blockIdx.x, j = threadIdx.x;
  int lo = lbound(batch, NN, b);
  int hi = lbound(batch, NN, b+1);
  float s = 0.f; float cnt = 0.f;
  for (int n = lo; n < hi; ++n){
    if (ntype[n] == 0){
      s += h3[(size_t)n*128 + j];
      cnt += 1.f;
    }
  }
  p[j] = s / fmaxf(cnt, 1.f);
  __syncthreads();
  float a = m1b[j];
  for (int k=0; k<128; ++k) a += p[k]*m1w[k*128 + j];
  red[j] = a; __syncthreads();
  for (int off=64; off>0; off>>=1){ if (j<off) red[j] += red[j+off]; __syncthreads(); }
  float mu = red[0] * (1.f/128.f);
  __syncthreads();
  float d = a - mu;
  red[j] = d*d; __syncthreads();
  for (int off=64; off>0; off>>=1){ if (j<off) red[j] += red[j+off]; __syncthreads(); }
  float var = red[0] * (1.f/128.f);
  __syncthreads();
  hb[j] = lrelu(d * rsqrtf(var + 1e-5f) * g1[j] + b1[j]);
  __syncthreads();
  float a2 = 0.f;
  if (j < 64){
    a2 = m2b[j];
    for (int k=0; k<128; ++k) a2 += hb[k]*m2w[k*64 + j];
  }
  red[j] = (j<64) ? a2 : 0.f; __syncthreads();
  for (int off=64; off>0; off>>=1){ if (j<off) red[j] += red[j+off]; __syncthreads(); }
  float mu2 = red[0] * (1.f/64.f);
  __syncthreads();
  float d2 = a2 - mu2;
  red[j] = (j<64) ? d2*d2 : 0.f; __syncthreads();
  for (int off=64; off>0; off>>=1){ if (j<off) red[j] += red[j+off]; __syncthreads(); }
  float var2 = red[0] * (1.f/64.f);
  __syncthreads();
  if (j < 64) hb[j] = lrelu(d2 * rsqrtf(var2 + 1e-5f) * g2[j] + b2[j]);
  __syncthreads();
  if (j == 0){
    float o = m3b[0];
    for (int k=0; k<64; ++k) o += hb[k]*m3w[k];
    out[b] = o;
  }
}

extern "C" void kernel_launch(void* const* d_in, const int* in_sizes, int n_in,
                              void* d_out, int out_size, void* d_ws, size_t ws_size,
                              hipStream_t stream)
{
  const float* x        = (const float*)d_in[0];
  const int*   ntype    = (const int*)d_in[1];
  const int*   ei       = (const int*)d_in[2];
  const float* eattr    = (const float*)d_in[3];
  const int*   batch    = (const int*)d_in[4];
  const float* vp_w     = (const float*)d_in[5];
  const float* vp_b     = (const float*)d_in[6];
  const float* type_emb = (const float*)d_in[7];
  const float* c1_wl = (const float*)d_in[8];  const float* c1_bl = (const float*)d_in[9];
  const float* c1_wr = (const float*)d_in[10]; const float* c1_br = (const float*)d_in[11];
  const float* c1_we = (const float*)d_in[12]; const float* c1_att= (const float*)d_in[13];
  const float* c1_bias=(const float*)d_in[14];
  const float* c2_wl = (const float*)d_in[15]; const float* c2_bl = (const float*)d_in[16];
  const float* c2_wr = (const float*)d_in[17]; const float* c2_br = (const float*)d_in[18];
  const float* c2_we = (const float*)d_in[19]; const float* c2_att= (const float*)d_in[20];
  const float* c2_bias=(const float*)d_in[21];
  const float* c3_wl = (const float*)d_in[22]; const float* c3_bl = (const float*)d_in[23];
  const float* c3_wr = (const float*)d_in[24]; const float* c3_br = (const float*)d_in[25];
  const float* c3_we = (const float*)d_in[26]; const float* c3_att= (const float*)d_in[27];
  const float* c3_bias=(const float*)d_in[28];
  const float* m1_w = (const float*)d_in[29]; const float* m1_b = (const float*)d_in[30];
  const float* ln1_g= (const float*)d_in[31]; const float* ln1_b= (const float*)d_in[32];
  const float* m2_w = (const float*)d_in[33]; const float* m2_b = (const float*)d_in[34];
  const float* ln2_g= (const float*)d_in[35]; const float* ln2_b= (const float*)d_in[36];
  const float* m3_w = (const float*)d_in[37]; const float* m3_b = (const float*)d_in[38];
  const int* esrc = ei;
  const int* edst = ei + NE;
  float* outp = (float*)d_out;
  (void)in_sizes; (void)n_in; (void)out_size; (void)ws_size;

  // ---- workspace arena ----
  char* w = (char*)d_ws;
  auto alloc = [&](size_t bytes) -> void* {
    void* p = (void*)w;
    w += (bytes + 255) & ~(size_t)255;
    return p;
  };
  unsigned short* h1bf = (unsigned short*)alloc((size_t)NN*1024*2);  // conv1 out, bf16
  unsigned short* X2   = (unsigned short*)alloc((size_t)NN*512*2);   // [xl2 | xr2] bf16
  unsigned short* h2bf = (unsigned short*)alloc((size_t)NN*256*2);   // conv2 out, bf16
  float* X3   = (float*)alloc((size_t)NN*256*4);    // [xl3 | xr3] fp32
  float* h3   = (float*)alloc((size_t)NN*128*4);    // conv3 out (type0 rows only)
  unsigned short* W2lT = (unsigned short*)alloc((size_t)256*1024*2);
  unsigned short* W2rT = (unsigned short*)alloc((size_t)256*1024*2);
  unsigned short* W3lT = (unsigned short*)alloc((size_t)128*256*2);
  unsigned short* W3rT = (unsigned short*)alloc((size_t)128*256*2);
  float* Ul   = (float*)alloc(1024*4);
  float* CTl  = (float*)alloc(2048*4);
  float* Ur   = (float*)alloc(1024*4);
  float* CTr  = (float*)alloc(2048*4);
  const int zero_words = NN + NN + NN;               // deg, rowctr, loop_sum
  float* zbase = (float*)alloc((size_t)zero_words*4);
  int*   deg      = (int*)zbase;
  int*   rowctr   = (int*)(zbase + NN);
  float* loop_sum = zbase + 2*NN;
  float* loop_attr= (float*)alloc((size_t)NN*4);
  int*   rowptr   = (int*)alloc((size_t)(NN+1)*4);
  int*   srcs     = (int*)alloc((size_t)NE*4);
  float* eav      = (float*)alloc((size_t)NE*4);

  // ---- pipeline ----
  zero_kernel<<<(zero_words+255)/256, 256, 0, stream>>>(zbase, zero_words);
  csr_count_kernel<<<(NE+255)/256, 256, 0, stream>>>(edst, eattr, deg, loop_sum);
  scan_kernel<<<1, 1024, 0, stream>>>(deg, loop_sum, rowptr, loop_attr);
  csr_fill_kernel<<<(NE+255)/256, 256, 0, stream>>>(esrc, edst, eattr, rowptr, rowctr, srcs, eav);
  precompute_c1_kernel<<<4, 256, 0, stream>>>(vp_w, vp_b, type_emb, c1_wl, c1_bl, c1_wr, c1_br,
                                              Ul, CTl, Ur, CTr);
  transpose_cast_kernel<<<dim3(16,4), 256, 0, stream>>>(c2_wl, W2lT, 1024, 256);
  transpose_cast_kernel<<<dim3(16,4), 256, 0, stream>>>(c2_wr, W2rT, 1024, 256);
  transpose_cast_kernel<<<dim3(4,2),  256, 0, stream>>>(c3_wl, W3lT, 256, 128);
  transpose_cast_kernel<<<dim3(4,2),  256, 0, stream>>>(c3_wr, W3rT, 256, 128);
  conv1_kernel<<<NN, 256, 0, stream>>>(rowptr, srcs, eav, loop_attr, x, ntype,
                                       Ul, CTl, Ur, CTr, c1_we, c1_att, c1_bias, h1bf);
  // c2: X2[10000,512] bf16 = [h1@wl+bl | h1@wr+br], K=1024, NcH=256
  // cgrid=8, rgrid=157 -> 8*8*ceil(157/8)=1280 blocks
  gemm_dual_mfma<true><<<8*8*20, 256, 0, stream>>>(
      (const short*)h1bf, (const short*)W2lT, (const short*)W2rT, c2_bl, c2_br,
      (void*)X2, NN, 1024, 256, 8, 157);
  conv_kernel<2,64,4,false,true,true><<<NN, 64, 0, stream>>>(rowptr, srcs, eav, loop_attr, ntype,
                                                   (const void*)X2, 512, 256, c2_we, c2_att, c2_bias, h2bf);
  // c3: X3[10000,256] fp32 = [h2@wl+bl | h2@wr+br], K=256, NcH=128
  // cgrid=4, rgrid=157 -> 8*4*ceil(157/8)=640 blocks
  gemm_dual_mfma<false><<<8*4*20, 256, 0, stream>>>(
      (const short*)h2bf, (const short*)W3lT, (const short*)W3rT, c3_bl, c3_br,
      (void*)X3, NN, 256, 128, 4, 157);
  conv_kernel<1,64,2,true,false,false><<<NN, 64, 0, stream>>>(rowptr, srcs, eav, loop_attr, ntype,
                                                  (const void*)X3, 256, 128, c3_we, c3_att, c3_bias, h3);
  head_kernel<<<NBATCH, 128, 0, stream>>>(h3, ntype, batch, m1_w, m1_b, ln1_g, ln1_b,
                                          m2_w, m2_b, ln2_g, ln2_b, m3_w, m3_b, outp);
}

// Round 6
// 407.896 us; speedup vs baseline: 1.3388x; 1.0100x over previous
//
#include <hip/hip_runtime.h>
#include <math.h>

#define NN 10000
#define NE 100000
#define NBATCH 64

typedef short bf16x8 __attribute__((ext_vector_type(8)));
typedef float f32x4 __attribute__((ext_vector_type(4)));

__device__ __forceinline__ float lrelu(float v){ return v > 0.f ? v : 0.2f*v; }

// fp32 -> bf16 round-to-nearest-even
__device__ __forceinline__ unsigned short f2bf(float x){
  unsigned int u = __float_as_uint(x);
  u += 0x7fffu + ((u >> 16) & 1u);
  return (unsigned short)(u >> 16);
}
__device__ __forceinline__ float bf2f(unsigned short u){
  return __uint_as_float(((unsigned int)u) << 16);
}

// ---------------- prep: zero + c1 precompute + 4 weight transposes (fused) -------------
// blocks: [0,64) c2_wl T, [64,128) c2_wr T, [128,136) c3_wl T, [136,144) c3_wr T,
//         [144,148) precompute_c1, [148,180) zero zbase
__global__ __launch_bounds__(256) void prep_kernel(
    const float* __restrict__ vp_w, const float* __restrict__ vp_b,
    const float* __restrict__ type_emb,
    const float* __restrict__ c1_wl, const float* __restrict__ c1_bl,
    const float* __restrict__ c1_wr, const float* __restrict__ c1_br,
    float* __restrict__ Ul, float* __restrict__ CTl,
    float* __restrict__ Ur, float* __restrict__ CTr,
    const float* __restrict__ c2_wl, const float* __restrict__ c2_wr,
    const float* __restrict__ c3_wl, const float* __restrict__ c3_wr,
    unsigned short* __restrict__ W2lT, unsigned short* __restrict__ W2rT,
    unsigned short* __restrict__ W3lT, unsigned short* __restrict__ W3rT,
    float* __restrict__ zbase, int zero_words)
{
  __shared__ float t[64][65];
  int b = blockIdx.x;
  int tid = threadIdx.x;
  if (b < 144){
    const float* in; unsigned short* out; int K, N, idx;
    if (b < 64)      { in=c2_wl; out=W2lT; K=1024; N=256; idx=b; }
    else if (b <128) { in=c2_wr; out=W2rT; K=1024; N=256; idx=b-64; }
    else if (b <136) { in=c3_wl; out=W3lT; K=256;  N=128; idx=b-128; }
    else             { in=c3_wr; out=W3rT; K=256;  N=128; idx=b-136; }
    int K64 = K >> 6;
    int kx = idx % K64, nx = idx / K64;
    int k0 = kx*64, n0 = nx*64;
    int lr = tid >> 4;
    int lc = (tid & 15) * 4;
#pragma unroll
    for (int i=0;i<4;++i){
      int r = lr + i*16;
      float4 v = *(const float4*)(in + (size_t)(k0+r)*N + n0 + lc);
      t[r][lc+0]=v.x; t[r][lc+1]=v.y; t[r][lc+2]=v.z; t[r][lc+3]=v.w;
    }
    __syncthreads();
    int sr = tid >> 3;
    int sc = (tid & 7) * 8;
#pragma unroll
    for (int i=0;i<2;++i){
      int n = sr + i*32;
      unsigned short tmp[8];
#pragma unroll
      for (int j=0;j<8;++j) tmp[j] = f2bf(t[sc+j][n]);
      unsigned short* op = out + (size_t)(n0+n)*K + k0 + sc;
      *(ushort4*)op       = make_ushort4(tmp[0],tmp[1],tmp[2],tmp[3]);
      *(ushort4*)(op + 4) = make_ushort4(tmp[4],tmp[5],tmp[6],tmp[7]);
    }
  } else if (b < 148){
    int j = (b-144)*256 + tid;
    float ul=0.f, c0l=0.f, c1l=0.f, ur=0.f, c0r=0.f, c1r=0.f;
    for (int k=0; k<128; ++k){
      float a = c1_wl[k*1024 + j], bb = c1_wr[k*1024 + j];
      float vw = vp_w[k], vb = vp_b[k], t0 = type_emb[k], t1 = type_emb[128+k];
      ul += vw*a; ur += vw*bb;
      c0l += (vb+t0)*a; c1l += (vb+t1)*a;
      c0r += (vb+t0)*bb; c1r += (vb+t1)*bb;
    }
    Ul[j]=ul; Ur[j]=ur;
    CTl[j]      = c0l + c1_bl[j];
    CTl[1024+j] = c1l + c1_bl[j];
    CTr[j]      = c0r + c1_br[j];
    CTr[1024+j] = c1r + c1_br[j];
  } else {
    for (int i = (b-148)*256 + tid; i < zero_words; i += 32*256)
      zbase[i] = 0.f;
  }
}

// ---------------- fused CSR build: count -> (last block) scan -> fill ----------------
// 98 blocks x 1024 thr (co-resident: 98*16=1568 waves << 8192 capacity).
// Cross-block comm strictly via device-scope atomics (XCD-safe).
__global__ __launch_bounds__(1024) void csr_kernel(
    const int* __restrict__ src, const int* __restrict__ dst, const float* __restrict__ ea,
    int* __restrict__ deg, float* __restrict__ loop_sum,
    int* __restrict__ rowptr, float* __restrict__ loop_attr,
    int* __restrict__ rowctr, int* __restrict__ srcs, float* __restrict__ eav,
    int* __restrict__ sync_)
{
  int tid = threadIdx.x;
  int e = blockIdx.x*1024 + tid;
  int d_ = 0; float eav_ = 0.f;
  bool active = e < NE;
  if (active){
    d_ = dst[e]; eav_ = ea[e];
    atomicAdd(&deg[d_], 1);
    atomicAdd(&loop_sum[d_], eav_);
  }
  __threadfence();
  __syncthreads();
  __shared__ int amlast;
  if (tid == 0) amlast = (atomicAdd(&sync_[0], 1) == (int)gridDim.x - 1);
  __syncthreads();
  if (amlast){
    __shared__ int wsum[16];
    __shared__ int carry_s;
    int lane = tid & 63, wid = tid >> 6;
    if (tid == 0) carry_s = 0;
    __syncthreads();
    for (int base = 0; base < NN; base += 1024){
      int i = base + tid;
      int v = 0; float ls = 0.f;
      if (i < NN){ v = atomicAdd(&deg[i], 0); ls = atomicAdd(&loop_sum[i], 0.f); }
      int incl = v;
#pragma unroll
      for (int off=1; off<64; off<<=1){
        int tt = __shfl_up(incl, off, 64);
        if (lane >= off) incl += tt;
      }
      if (lane == 63) wsum[wid] = incl;
      __syncthreads();
      int pre = carry_s;
      for (int w2=0; w2<wid; ++w2) pre += wsum[w2];
      if (i < NN){
        rowptr[i] = pre + incl - v;                          // exclusive scan
        loop_attr[i] = ls / fmaxf((float)v, 1.f);            // fill='mean'
      }
      __syncthreads();
      if (tid == 0){
        int t2 = 0;
        for (int w2=0; w2<16; ++w2) t2 += wsum[w2];
        carry_s += t2;
      }
      __syncthreads();
    }
    if (tid == 0) rowptr[NN] = carry_s;
    __threadfence();
    __syncthreads();
    if (tid == 0) atomicExch(&sync_[1], 1);
  }
  if (tid == 0){
    while (atomicAdd(&sync_[1], 0) == 0) __builtin_amdgcn_s_sleep(16);
  }
  __syncthreads();
  if (active){
    int p = atomicAdd(&rowptr[d_], 0) + atomicAdd(&rowctr[d_], 1);
    srcs[p] = src[e];
    eav[p] = eav_;
  }
}

// ---------------- conv1: fused GATv2 with on-the-fly xl/xr (H=8, C=128), bf16 out --------
__global__ __launch_bounds__(256) void conv1_kernel(
    const int* __restrict__ rowptr, const int* __restrict__ srcs, const float* __restrict__ eav,
    const float* __restrict__ loop_attr, const float* __restrict__ x, const int* __restrict__ ntype,
    const float* __restrict__ Ul, const float* __restrict__ CTl,
    const float* __restrict__ Ur, const float* __restrict__ CTr,
    const float* __restrict__ we, const float* __restrict__ att, const float* __restrict__ bias,
    unsigned short* __restrict__ out)
{
  const int TPH = 32;               // threads per head (8 heads x 32 = 256)
  int n = blockIdx.x;
  int tid = threadIdx.x;
  int ch0 = tid * 4;
  float wev[4], atv[4], biv[4], ulv[4], c0l[4], c1l[4], xrv[4];
  {
    float urv[4], c0r[4], c1r[4];
#pragma unroll
    for (int v=0; v<4; ++v){
      int ch = ch0 + v;
      wev[v] = we[ch]; atv[v] = att[ch]; biv[v] = bias[ch];
      ulv[v] = Ul[ch]; c0l[v] = CTl[ch]; c1l[v] = CTl[1024+ch];
      urv[v] = Ur[ch]; c0r[v] = CTr[ch]; c1r[v] = CTr[1024+ch];
    }
    float xn = x[n];
    int tn = ntype[n];
#pragma unroll
    for (int v=0; v<4; ++v) xrv[v] = xn*urv[v] + (tn ? c1r[v] : c0r[v]);
  }
  float acc[4] = {0.f,0.f,0.f,0.f};
  float m = -INFINITY, l = 0.f;
  int beg = rowptr[n], end = rowptr[n+1];
  for (int j = beg; j <= end; ++j){  // j==end is the self-loop
    int s; float ea;
    if (j < end){ s = srcs[j]; ea = eav[j]; }
    else        { s = n;       ea = loop_attr[n]; }
    float xs = x[s];
    int ts = ntype[s];
    float xlv[4];
#pragma unroll
    for (int v=0; v<4; ++v) xlv[v] = xs*ulv[v] + (ts ? c1l[v] : c0l[v]);
    float p = 0.f;
#pragma unroll
    for (int v=0; v<4; ++v){
      float z = xlv[v] + xrv[v] + ea*wev[v];
      p += atv[v]*lrelu(z);
    }
#pragma unroll
    for (int mm=1; mm<TPH; mm<<=1) p += __shfl_xor(p, mm, 64);
    float mn = fmaxf(m, p);
    float sc = __expf(m - mn);
    float pe = __expf(p - mn);
    l = l*sc + pe;
    m = mn;
#pragma unroll
    for (int v=0; v<4; ++v) acc[v] = acc[v]*sc + pe*xlv[v];
  }
  float inv = 1.f/l;
  size_t baseo = (size_t)n*1024 + ch0;
  ushort4 o;
  o.x = f2bf(lrelu(acc[0]*inv + biv[0]));
  o.y = f2bf(lrelu(acc[1]*inv + biv[1]));
  o.z = f2bf(lrelu(acc[2]*inv + biv[2]));
  o.w = f2bf(lrelu(acc[3]*inv + biv[3]));
  *(ushort4*)(out + baseo) = o;
}

// ---------------- generic fused GATv2 conv (concat xl|xr input layout) ----------------
template<int H, int THREADS, int VPT, bool ONLY0, bool OUTBF, bool INBF>
__global__ __launch_bounds__(THREADS) void conv_kernel(
    const int* __restrict__ rowptr, const int* __restrict__ srcs, const float* __restrict__ eav,
    const float* __restrict__ loop_attr, const int* __restrict__ ntype,
    const void* __restrict__ Xv, int stride, int xr_off,
    const float* __restrict__ we, const float* __restrict__ att, const float* __restrict__ bias,
    void* __restrict__ out)
{
  const int HC = THREADS*VPT;
  const int TPH = THREADS/H;
  int n = blockIdx.x;
  if (ONLY0 && ntype[n] != 0) return;
  int tid = threadIdx.x;
  int ch0 = tid * VPT;
  const float* Xf = (const float*)Xv;
  const unsigned short* Xb = (const unsigned short*)Xv;
  float wev[VPT], atv[VPT], biv[VPT], xrv[VPT], acc[VPT];
#pragma unroll
  for (int v=0; v<VPT; ++v){
    int ch = ch0+v;
    wev[v]=we[ch]; atv[v]=att[ch]; biv[v]=bias[ch];
    acc[v]=0.f;
  }
  if constexpr (INBF){
    ushort4 q = *(const ushort4*)(Xb + (size_t)n*stride + xr_off + ch0);
    xrv[0]=bf2f(q.x); xrv[1]=bf2f(q.y); xrv[2]=bf2f(q.z); xrv[3]=bf2f(q.w);
  } else {
#pragma unroll
    for (int v=0; v<VPT; ++v) xrv[v]=Xf[(size_t)n*stride + xr_off + ch0+v];
  }
  float m=-INFINITY, l=0.f;
  int beg=rowptr[n], end=rowptr[n+1];
  for (int j=beg; j<=end; ++j){
    int s; float ea;
    if (j<end){ s=srcs[j]; ea=eav[j]; } else { s=n; ea=loop_attr[n]; }
    float xlv[VPT];
    if constexpr (INBF){
      ushort4 q = *(const ushort4*)(Xb + (size_t)s*stride + ch0);
      xlv[0]=bf2f(q.x); xlv[1]=bf2f(q.y); xlv[2]=bf2f(q.z); xlv[3]=bf2f(q.w);
    } else if constexpr (VPT == 4){
      float4 q = *(const float4*)(Xf + (size_t)s*stride + ch0);
      xlv[0]=q.x; xlv[1]=q.y; xlv[2]=q.z; xlv[3]=q.w;
    } else {
      float2 q = *(const float2*)(Xf + (size_t)s*stride + ch0);
      xlv[0]=q.x; xlv[1]=q.y;
    }
    float p=0.f;
#pragma unroll
    for (int v=0; v<VPT; ++v){
      float z = xlv[v]+xrv[v]+ea*wev[v];
      p += atv[v]*lrelu(z);
    }
#pragma unroll
    for (int mm=1; mm<TPH; mm<<=1) p += __shfl_xor(p, mm, 64);
    float mn=fmaxf(m,p), sc=__expf(m-mn), pe=__expf(p-mn);
    l=l*sc+pe; m=mn;
#pragma unroll
    for (int v=0; v<VPT; ++v) acc[v]=acc[v]*sc+pe*xlv[v];
  }
  float inv=1.f/l;
  size_t baseo=(size_t)n*HC+ch0;
  if constexpr (OUTBF){
    unsigned short* ob = (unsigned short*)out;
    ushort4 o;
    o.x = f2bf(lrelu(acc[0]*inv+biv[0]));
    o.y = f2bf(lrelu(acc[1]*inv+biv[1]));
    o.z = f2bf(lrelu(acc[2]*inv+biv[2]));
    o.w = f2bf(lrelu(acc[3]*inv+biv[3]));
    *(ushort4*)(ob + baseo) = o;
  } else {
    float* of = (float*)out;
#pragma unroll
    for (int v=0; v<VPT; ++v) of[baseo+v]=lrelu(acc[v]*inv+biv[v]);
  }
}

// ---------------- bf16 MFMA dual GEMM, register-double-buffered ----------------
// Out[M, 2*NcH] = [A@Wl + bl | A@Wr + br]; A[M][K] bf16, WT[NcH][K] bf16.
// Block 256 thr = 4 waves stacked on rows: tile 128x64; wave tile 32x64 =
// 2x4 mfma_16x16x32 (8 MFMA / 6 loads per k-step), explicit 2-stage pipeline.
// XCD swizzle: all col-groups of one row-group on one XCD (A strip L2 reuse).
// cgrid = 2*NcH/64, rgrid = ceil(M/128); launch 8*cgrid*ceil(rgrid/8) blocks.
template<bool OUTBF>
__global__ __launch_bounds__(256) void gemm_dual_mfma(
    const short* __restrict__ Abf,
    const short* __restrict__ WlT, const short* __restrict__ WrT,
    const float* __restrict__ bl, const float* __restrict__ br,
    void* __restrict__ Out, int M, int K, int NcH, int cgrid, int rgrid)
{
  int id = blockIdx.x;
  int xcd = id & 7;
  int slot = id >> 3;
  int nb = slot % cgrid;
  int rowgroup = (slot / cgrid) * 8 + xcd;
  if (rowgroup >= rgrid) return;
  int row0 = rowgroup * 128;
  int NC2 = 2*NcH;
  int halfx = NcH >> 6;
  int isR = nb >= halfx;
  const short* WT = isR ? WrT : WlT;
  const float* bias = isR ? br : bl;
  int col0 = (nb - (isR ? halfx : 0)) * 64;
  int gcol0 = nb * 64;
  int tid = threadIdx.x;
  int lane = tid & 63, wave = tid >> 6;
  int quad = lane >> 4, l16 = lane & 15;

  int ar0 = row0 + wave*32 + l16;
  int ar1 = ar0 + 16;
  int car0 = ar0 < M ? ar0 : M-1;   // clamped rows never stored
  int car1 = ar1 < M ? ar1 : M-1;
  const short* ap0 = Abf + (size_t)car0*K + quad*8;
  const short* ap1 = Abf + (size_t)car1*K + quad*8;
  const short* bq0 = WT + (size_t)(col0 +  0 + l16)*K + quad*8;
  const short* bq1 = WT + (size_t)(col0 + 16 + l16)*K + quad*8;
  const short* bq2 = WT + (size_t)(col0 + 32 + l16)*K + quad*8;
  const short* bq3 = WT + (size_t)(col0 + 48 + l16)*K + quad*8;
  float bias0 = bias[col0 +  0 + l16];
  float bias1 = bias[col0 + 16 + l16];
  float bias2 = bias[col0 + 32 + l16];
  float bias3 = bias[col0 + 48 + l16];

  f32x4 acc00={0.f,0.f,0.f,0.f}, acc01={0.f,0.f,0.f,0.f};
  f32x4 acc02={0.f,0.f,0.f,0.f}, acc03={0.f,0.f,0.f,0.f};
  f32x4 acc10={0.f,0.f,0.f,0.f}, acc11={0.f,0.f,0.f,0.f};
  f32x4 acc12={0.f,0.f,0.f,0.f}, acc13={0.f,0.f,0.f,0.f};

  bf16x8 a0A,a1A,b0A,b1A,b2A,b3A, a0B,a1B,b0B,b1B,b2B,b3B;

#define LDST(S,k0) { a0##S=*(const bf16x8*)(ap0+(k0)); a1##S=*(const bf16x8*)(ap1+(k0)); \
  b0##S=*(const bf16x8*)(bq0+(k0)); b1##S=*(const bf16x8*)(bq1+(k0)); \
  b2##S=*(const bf16x8*)(bq2+(k0)); b3##S=*(const bf16x8*)(bq3+(k0)); }
#define MFMAS(S) { \
  acc00=__builtin_amdgcn_mfma_f32_16x16x32_bf16(a0##S,b0##S,acc00,0,0,0); \
  acc01=__builtin_amdgcn_mfma_f32_16x16x32_bf16(a0##S,b1##S,acc01,0,0,0); \
  acc02=__builtin_amdgcn_mfma_f32_16x16x32_bf16(a0##S,b2##S,acc02,0,0,0); \
  acc03=__builtin_amdgcn_mfma_f32_16x16x32_bf16(a0##S,b3##S,acc03,0,0,0); \
  acc10=__builtin_amdgcn_mfma_f32_16x16x32_bf16(a1##S,b0##S,acc10,0,0,0); \
  acc11=__builtin_amdgcn_mfma_f32_16x16x32_bf16(a1##S,b1##S,acc11,0,0,0); \
  acc12=__builtin_amdgcn_mfma_f32_16x16x32_bf16(a1##S,b2##S,acc12,0,0,0); \
  acc13=__builtin_amdgcn_mfma_f32_16x16x32_bf16(a1##S,b3##S,acc13,0,0,0); }

  int nk = K >> 5;   // assumed even (K=1024 -> 32, K=256 -> 8)
  LDST(A,0)
  for (int i=0; i<nk; i+=2){
    LDST(B,(i+1)<<5)            // prefetch odd stage before even MFMAs
    MFMAS(A)
    if (i+2 < nk) LDST(A,(i+2)<<5)
    MFMAS(B)
  }
#undef LDST
#undef MFMAS

  int rb = row0 + wave*32 + quad*4;
#pragma unroll
  for (int r=0; r<4; ++r){
    int rr = rb + r;
    int rr2 = rr + 16;
    if constexpr (OUTBF){
      unsigned short* ob = (unsigned short*)Out;
      if (rr < M){
        size_t base = (size_t)rr*NC2 + gcol0 + l16;
        ob[base   ] = f2bf(acc00[r] + bias0);
        ob[base+16] = f2bf(acc01[r] + bias1);
        ob[base+32] = f2bf(acc02[r] + bias2);
        ob[base+48] = f2bf(acc03[r] + bias3);
      }
      if (rr2 < M){
        size_t base = (size_t)rr2*NC2 + gcol0 + l16;
        ob[base   ] = f2bf(acc10[r] + bias0);
        ob[base+16] = f2bf(acc11[r] + bias1);
        ob[base+32] = f2bf(acc12[r] + bias2);
        ob[base+48] = f2bf(acc13[r] + bias3);
      }
    } else {
      float* of = (float*)Out;
      if (rr < M){
        size_t base = (size_t)rr*NC2 + gcol0 + l16;
        of[base   ] = acc00[r] + bias0;
        of[base+16] = acc01[r] + bias1;
        of[base+32] = acc02[r] + bias2;
        of[base+48] = acc03[r] + bias3;
      }
      if (rr2 < M){
        size_t base = (size_t)rr2*NC2 + gcol0 + l16;
        of[base   ] = acc10[r] + bias0;
        of[base+16] = acc11[r] + bias1;
        of[base+32] = acc12[r] + bias2;
        of[base+48] = acc13[r] + bias3;
      }
    }
  }
}

// ---------------- fused pool (sorted batch, binary search) + MLP head ----------------
__device__ __forceinline__ int lbound(const int* __restrict__ a, int n, int key){
  int lo = 0, hi = n;
  while (lo < hi){ int mid = (lo+hi) >> 1; if (a[mid] < key) lo = mid+1; else hi = mid; }
  return lo;
}

__global__ __launch_bounds__(128) void head_kernel(
    const float* __restrict__ h3, const int* __restrict__ ntype, const int* __restrict__ batch,
    const float* __restrict__ m1w, const float* __restrict__ m1b,
    const float* __restrict__ g1, const float* __restrict__ b1,
    const float* __restrict__ m2w, const float* __restrict__ m2b,
    const float* __restrict__ g2, const float* __restrict__ b2,
    const float* __restrict__ m3w, const float* __restrict__ m3b,
    float* __restrict__ out)
{
  __shared__ float p[128];
  __shared__ float hb[128];
  __shared__ float red[128];
  int b = blockIdx.x, j = threadIdx.x;
  int lo = lbound(batch, NN, b);
  int hi = lbound(batch, NN, b+1);
  float s = 0.f; float cnt = 0.f;
  for (int n = lo; n < hi; ++n){
    if (ntype[n] == 0){
      s += h3[(size_t)n*128 + j];
      cnt += 1.f;
    }
  }
  p[j] = s / fmaxf(cnt, 1.f);
  __syncthreads();
  float a = m1b[j];
  for (int k=0; k<128; ++k) a += p[k]*m1w[k*128 + j];
  red[j] = a; __syncthreads();
  for (int off=64; off>0; off>>=1){ if (j<off) red[j] += red[j+off]; __syncthreads(); }
  float mu = red[0] * (1.f/128.f);
  __syncthreads();
  float d = a - mu;
  red[j] = d*d; __syncthreads();
  for (int off=64; off>0; off>>=1){ if (j<off) red[j] += red[j+off]; __syncthreads(); }
  float var = red[0] * (1.f/128.f);
  __syncthreads();
  hb[j] = lrelu(d * rsqrtf(var + 1e-5f) * g1[j] + b1[j]);
  __syncthreads();
  float a2 = 0.f;
  if (j < 64){
    a2 = m2b[j];
    for (int k=0; k<128; ++k) a2 += hb[k]*m2w[k*64 + j];
  }
  red[j] = (j<64) ? a2 : 0.f; __syncthreads();
  for (int off=64; off>0; off>>=1){ if (j<off) red[j] += red[j+off]; __syncthreads(); }
  float mu2 = red[0] * (1.f/64.f);
  __syncthreads();
  float d2 = a2 - mu2;
  red[j] = (j<64) ? d2*d2 : 0.f; __syncthreads();
  for (int off=64; off>0; off>>=1){ if (j<off) red[j] += red[j+off]; __syncthreads(); }
  float var2 = red[0] * (1.f/64.f);
  __syncthreads();
  if (j < 64) hb[j] = lrelu(d2 * rsqrtf(var2 + 1e-5f) * g2[j] + b2[j]);
  __syncthreads();
  if (j == 0){
    float o = m3b[0];
    for (int k=0; k<64; ++k) o += hb[k]*m3w[k];
    out[b] = o;
  }
}

extern "C" void kernel_launch(void* const* d_in, const int* in_sizes, int n_in,
                              void* d_out, int out_size, void* d_ws, size_t ws_size,
                              hipStream_t stream)
{
  const float* x        = (const float*)d_in[0];
  const int*   ntype    = (const int*)d_in[1];
  const int*   ei       = (const int*)d_in[2];
  const float* eattr    = (const float*)d_in[3];
  const int*   batch    = (const int*)d_in[4];
  const float* vp_w     = (const float*)d_in[5];
  const float* vp_b     = (const float*)d_in[6];
  const float* type_emb = (const float*)d_in[7];
  const float* c1_wl = (const float*)d_in[8];  const float* c1_bl = (const float*)d_in[9];
  const float* c1_wr = (const float*)d_in[10]; const float* c1_br = (const float*)d_in[11];
  const float* c1_we = (const float*)d_in[12]; const float* c1_att= (const float*)d_in[13];
  const float* c1_bias=(const float*)d_in[14];
  const float* c2_wl = (const float*)d_in[15]; const float* c2_bl = (const float*)d_in[16];
  const float* c2_wr = (const float*)d_in[17]; const float* c2_br = (const float*)d_in[18];
  const float* c2_we = (const float*)d_in[19]; const float* c2_att= (const float*)d_in[20];
  const float* c2_bias=(const float*)d_in[21];
  const float* c3_wl = (const float*)d_in[22]; const float* c3_bl = (const float*)d_in[23];
  const float* c3_wr = (const float*)d_in[24]; const float* c3_br = (const float*)d_in[25];
  const float* c3_we = (const float*)d_in[26]; const float* c3_att= (const float*)d_in[27];
  const float* c3_bias=(const float*)d_in[28];
  const float* m1_w = (const float*)d_in[29]; const float* m1_b = (const float*)d_in[30];
  const float* ln1_g= (const float*)d_in[31]; const float* ln1_b= (const float*)d_in[32];
  const float* m2_w = (const float*)d_in[33]; const float* m2_b = (const float*)d_in[34];
  const float* ln2_g= (const float*)d_in[35]; const float* ln2_b= (const float*)d_in[36];
  const float* m3_w = (const float*)d_in[37]; const float* m3_b = (const float*)d_in[38];
  const int* esrc = ei;
  const int* edst = ei + NE;
  float* outp = (float*)d_out;
  (void)in_sizes; (void)n_in; (void)out_size; (void)ws_size;

  // ---- workspace arena ----
  char* w = (char*)d_ws;
  auto alloc = [&](size_t bytes) -> void* {
    void* p = (void*)w;
    w += (bytes + 255) & ~(size_t)255;
    return p;
  };
  unsigned short* h1bf = (unsigned short*)alloc((size_t)NN*1024*2);  // conv1 out, bf16
  unsigned short* X2   = (unsigned short*)alloc((size_t)NN*512*2);   // [xl2 | xr2] bf16
  unsigned short* h2bf = (unsigned short*)alloc((size_t)NN*256*2);   // conv2 out, bf16
  float* X3   = (float*)alloc((size_t)NN*256*4);    // [xl3 | xr3] fp32
  float* h3   = (float*)alloc((size_t)NN*128*4);    // conv3 out (type0 rows only)
  unsigned short* W2lT = (unsigned short*)alloc((size_t)256*1024*2);
  unsigned short* W2rT = (unsigned short*)alloc((size_t)256*1024*2);
  unsigned short* W3lT = (unsigned short*)alloc((size_t)128*256*2);
  unsigned short* W3rT = (unsigned short*)alloc((size_t)128*256*2);
  float* Ul   = (float*)alloc(1024*4);
  float* CTl  = (float*)alloc(2048*4);
  float* Ur   = (float*)alloc(1024*4);
  float* CTr  = (float*)alloc(2048*4);
  const int zero_words = 3*NN + 2;                   // deg, rowctr, loop_sum, sync[2]
  float* zbase = (float*)alloc((size_t)zero_words*4);
  int*   deg      = (int*)zbase;
  int*   rowctr   = (int*)(zbase + NN);
  float* loop_sum = zbase + 2*NN;
  int*   sync_    = (int*)(zbase + 3*NN);
  float* loop_attr= (float*)alloc((size_t)NN*4);
  int*   rowptr   = (int*)alloc((size_t)(NN+1)*4);
  int*   srcs     = (int*)alloc((size_t)NE*4);
  float* eav      = (float*)alloc((size_t)NE*4);

  // ---- pipeline (8 dispatches) ----
  prep_kernel<<<180, 256, 0, stream>>>(vp_w, vp_b, type_emb,
      c1_wl, c1_bl, c1_wr, c1_br, Ul, CTl, Ur, CTr,
      c2_wl, c2_wr, c3_wl, c3_wr, W2lT, W2rT, W3lT, W3rT,
      zbase, zero_words);
  csr_kernel<<<(NE+1023)/1024, 1024, 0, stream>>>(esrc, edst, eattr,
      deg, loop_sum, rowptr, loop_attr, rowctr, srcs, eav, sync_);
  conv1_kernel<<<NN, 256, 0, stream>>>(rowptr, srcs, eav, loop_attr, x, ntype,
                                       Ul, CTl, Ur, CTr, c1_we, c1_att, c1_bias, h1bf);
  // c2: X2[10000,512] bf16 = [h1@wl+bl | h1@wr+br], K=1024, NcH=256
  // cgrid=8, rgrid=ceil(10000/128)=79 -> 8*8*10 = 640 blocks
  gemm_dual_mfma<true><<<640, 256, 0, stream>>>(
      (const short*)h1bf, (const short*)W2lT, (const short*)W2rT, c2_bl, c2_br,
      (void*)X2, NN, 1024, 256, 8, 79);
  conv_kernel<2,64,4,false,true,true><<<NN, 64, 0, stream>>>(rowptr, srcs, eav, loop_attr, ntype,
      (const void*)X2, 512, 256, c2_we, c2_att, c2_bias, h2bf);
  // c3: X3[10000,256] fp32 = [h2@wl+bl | h2@wr+br], K=256, NcH=128
  // cgrid=4, rgrid=79 -> 8*4*10 = 320 blocks
  gemm_dual_mfma<false><<<320, 256, 0, stream>>>(
      (const short*)h2bf, (const short*)W3lT, (const short*)W3rT, c3_bl, c3_br,
      (void*)X3, NN, 256, 128, 4, 79);
  conv_kernel<1,64,2,true,false,false><<<NN, 64, 0, stream>>>(rowptr, srcs, eav, loop_attr, ntype,
      (const void*)X3, 256, 128, c3_we, c3_att, c3_bias, h3);
  head_kernel<<<NBATCH, 128, 0, stream>>>(h3, ntype, batch, m1_w, m1_b, ln1_g, ln1_b,
                                          m2_w, m2_b, ln2_g, ln2_b, m3_w, m3_b, outp);
}